// Round 3
// baseline (317.660 us; speedup 1.0000x reference)
//
#include <hip/hip_runtime.h>
#include <hip/hip_bf16.h>
#include <stdint.h>

typedef __hip_bfloat16 bf16;

static constexpr int BB  = 2;    // batch
static constexpr int UU_ = 100;  // units
static constexpr int IND = 101;  // input dim (1 + U)
static constexpr int C1  = 200;  // layer-1 out channels
static constexpr int C2  = 100;  // layer-2 out channels
static constexpr float NEG = 0.2f;

__device__ __forceinline__ float bf2f(bf16 v) { return __bfloat162float(v); }

// dtype-flexible load/store for the harness-owned buffers (inputs + d_out).
// BF=0: fp32 buffers, BF=1: bf16 buffers.
template<int BF> __device__ __forceinline__ float ldf(const void* p, size_t i) {
  if constexpr (BF) return __bfloat162float(((const bf16*)p)[i]);
  else              return ((const float*)p)[i];
}
template<int BF> __device__ __forceinline__ void stf(void* p, size_t i, float v) {
  if constexpr (BF) ((bf16*)p)[i] = __float2bfloat16(v);
  else              ((float*)p)[i] = v;
}

// ---------------- dtype detector ----------------
// Reads the first 1024 words (4 KB) of `state` (>=8 MB under either dtype).
// bf16 data: byte1 of each word is a bf16 sign/exp byte -> (b&0x7F) in
// [0x3B,0x40] for ~N(0,1) values (~97%). fp32 data: byte1 is a random
// mantissa byte (~5% hit). flag = 1 (bf16) iff >=512 of 1024 hit.
__global__ void k_detect(const uint32_t* __restrict__ w, int* __restrict__ flag) {
  int t = threadIdx.x;
  int cnt = 0;
  for (int i = t; i < 1024; i += 64) {
    int b = (w[i] >> 8) & 0x7F;
    cnt += (b >= 0x3B && b <= 0x40) ? 1 : 0;
  }
#pragma unroll
  for (int off = 32; off > 0; off >>= 1) cnt += __shfl_xor(cnt, off);
  if (t == 0) *flag = (cnt >= 512) ? 1 : 0;
}

// ---------------- CSR build (dtype-independent) ----------------

__global__ void k_zero(int* __restrict__ p, int n) {
  int i = blockIdx.x * 256 + threadIdx.x;
  if (i < n) p[i] = 0;
}

__global__ void k_hist(const int* __restrict__ dst, int E, int* __restrict__ hist) {
  int e = blockIdx.x * 256 + threadIdx.x;
  if (e < E) atomicAdd(&hist[dst[e]], 1);
}

__global__ __launch_bounds__(1024) void k_scan(int* __restrict__ histcur,
                                               int* __restrict__ rowptr, int N, int E) {
  __shared__ int part[1024];
  int t = threadIdx.x;
  int CH = (N + 1023) / 1024;
  int beg = t * CH; if (beg > N) beg = N;
  int end = beg + CH; if (end > N) end = N;
  int s = 0;
  for (int i = beg; i < end; ++i) s += histcur[i];
  part[t] = s;
  __syncthreads();
  for (int off = 1; off < 1024; off <<= 1) {
    int v = (t >= off) ? part[t - off] : 0;
    __syncthreads();
    part[t] += v;
    __syncthreads();
  }
  int base = (t == 0) ? 0 : part[t - 1];
  for (int i = beg; i < end; ++i) {
    int h = histcur[i];
    rowptr[i] = base;
    histcur[i] = base;   // becomes insertion cursor
    base += h;
  }
  if (t == 1023) rowptr[N] = part[1023];
}

__global__ void k_scatter(const int* __restrict__ src, const int* __restrict__ dst, int E,
                          int* __restrict__ cursor, int* __restrict__ col) {
  int e = blockIdx.x * 256 + threadIdx.x;
  if (e < E) {
    int p = atomicAdd(&cursor[dst[e]], 1);
    col[p] = src[e];
  }
}

// ---------------- dense transforms (x @ W + b) -> bf16 tables ----------------

template<int BF>
__global__ __launch_bounds__(256) void k_xform1(
    const int* __restrict__ flag,
    const void* __restrict__ inp, const void* __restrict__ st,
    const void* __restrict__ Wl, const void* __restrict__ bl,
    const void* __restrict__ Wr, const void* __restrict__ br,
    bf16* __restrict__ xl, bf16* __restrict__ xr, int N) {
  if (*flag != BF) return;
  __shared__ __align__(16) float xrow[BB][8][104];
  int tid = threadIdx.x;
  int n0 = blockIdx.x * 8;
  for (int i = tid; i < BB * 8 * 104; i += 256) {
    int b = i / (8 * 104); int r = i % (8 * 104); int m = r / 104; int k = r % 104;
    int n = n0 + m;
    float v = 0.f;
    if (n < N && k < IND)
      v = (k == 0) ? ldf<BF>(inp, (size_t)b * N + n)
                   : ldf<BF>(st, ((size_t)b * N + n) * UU_ + (k - 1));
    xrow[b][m][k] = v;
  }
  __syncthreads();
  int c = tid;
  if (c >= C1) return;
  float al[16], ar[16];
#pragma unroll
  for (int i = 0; i < 16; ++i) { al[i] = 0.f; ar[i] = 0.f; }
  for (int kc = 0; kc < 100; kc += 4) {
    float wlv[4], wrv[4];
#pragma unroll
    for (int q = 0; q < 4; ++q) {
      wlv[q] = ldf<BF>(Wl, (size_t)(kc + q) * C1 + c);
      wrv[q] = ldf<BF>(Wr, (size_t)(kc + q) * C1 + c);
    }
#pragma unroll
    for (int b = 0; b < BB; ++b)
#pragma unroll
      for (int m = 0; m < 8; ++m) {
        const float4 x = *reinterpret_cast<const float4*>(&xrow[b][m][kc]);
        int i = b * 8 + m;
        al[i] = fmaf(x.w, wlv[3], fmaf(x.z, wlv[2], fmaf(x.y, wlv[1], fmaf(x.x, wlv[0], al[i]))));
        ar[i] = fmaf(x.w, wrv[3], fmaf(x.z, wrv[2], fmaf(x.y, wrv[1], fmaf(x.x, wrv[0], ar[i]))));
      }
  }
  { // tail k = 100
    float wl = ldf<BF>(Wl, (size_t)100 * C1 + c), wr = ldf<BF>(Wr, (size_t)100 * C1 + c);
#pragma unroll
    for (int b = 0; b < BB; ++b)
#pragma unroll
      for (int m = 0; m < 8; ++m) {
        float x = xrow[b][m][100]; int i = b * 8 + m;
        al[i] = fmaf(x, wl, al[i]); ar[i] = fmaf(x, wr, ar[i]);
      }
  }
  float blc = ldf<BF>(bl, c), brc = ldf<BF>(br, c);
#pragma unroll
  for (int b = 0; b < BB; ++b)
    for (int m = 0; m < 8; ++m) {
      int n = n0 + m;
      if (n < N) {
        size_t o = ((size_t)b * N + n) * C1 + c;
        xl[o] = __float2bfloat16(al[b * 8 + m] + blc);
        xr[o] = __float2bfloat16(ar[b * 8 + m] + brc);
      }
    }
}

// Layer 2: x = [inputs, r*state] (rs: bf16 internal table).
template<int BF>
__global__ __launch_bounds__(256) void k_xform2(
    const int* __restrict__ flag,
    const void* __restrict__ inp, const bf16* __restrict__ rs,
    const void* __restrict__ Wl, const void* __restrict__ bl,
    const void* __restrict__ Wr, const void* __restrict__ br,
    bf16* __restrict__ xl, bf16* __restrict__ xr, int N) {
  if (*flag != BF) return;
  __shared__ __align__(16) float xrow[BB][8][104];
  int tid = threadIdx.x;
  int n0 = blockIdx.x * 8;
  for (int i = tid; i < BB * 8 * 104; i += 256) {
    int b = i / (8 * 104); int r = i % (8 * 104); int m = r / 104; int k = r % 104;
    int n = n0 + m;
    float v = 0.f;
    if (n < N && k < IND)
      v = (k == 0) ? ldf<BF>(inp, (size_t)b * N + n)
                   : bf2f(rs[((size_t)b * N + n) * UU_ + (k - 1)]);
    xrow[b][m][k] = v;
  }
  __syncthreads();
  int t = tid;
  if (t >= 2 * C2) return;
  int c = t % C2;
  const void* W    = (t < C2) ? Wl : Wr;
  const void* bias = (t < C2) ? bl : br;
  bf16* out        = (t < C2) ? xl : xr;
  float acc[16];
#pragma unroll
  for (int i = 0; i < 16; ++i) acc[i] = 0.f;
  for (int kc = 0; kc < 100; kc += 4) {
    float wv[4];
#pragma unroll
    for (int q = 0; q < 4; ++q) wv[q] = ldf<BF>(W, (size_t)(kc + q) * C2 + c);
#pragma unroll
    for (int b = 0; b < BB; ++b)
#pragma unroll
      for (int m = 0; m < 8; ++m) {
        const float4 x = *reinterpret_cast<const float4*>(&xrow[b][m][kc]);
        int i = b * 8 + m;
        acc[i] = fmaf(x.w, wv[3], fmaf(x.z, wv[2], fmaf(x.y, wv[1], fmaf(x.x, wv[0], acc[i]))));
      }
  }
  { // tail k = 100
    float w = ldf<BF>(W, (size_t)100 * C2 + c);
#pragma unroll
    for (int b = 0; b < BB; ++b)
#pragma unroll
      for (int m = 0; m < 8; ++m) {
        float x = xrow[b][m][100]; int i = b * 8 + m;
        acc[i] = fmaf(x, w, acc[i]);
      }
  }
  float bc = ldf<BF>(bias, c);
#pragma unroll
  for (int b = 0; b < BB; ++b)
    for (int m = 0; m < 8; ++m) {
      int n = n0 + m;
      if (n < N) out[((size_t)b * N + n) * C2 + c] = __float2bfloat16(acc[b * 8 + m] + bc);
    }
}

// ---------------- GATv2 aggregation: one wave per (b, dst), online softmax ----------------

template<int BF>
__global__ __launch_bounds__(256) void k_agg1(
    const int* __restrict__ flag,
    const bf16* __restrict__ xl, const bf16* __restrict__ xr,
    const int* __restrict__ rowptr, const int* __restrict__ col,
    const void* __restrict__ att, const void* __restrict__ bg, const void* __restrict__ bias0,
    const void* __restrict__ st, bf16* __restrict__ rs, void* __restrict__ uu, int N) {
  if (*flag != BF) return;
  int w = threadIdx.x >> 6, lane = threadIdx.x & 63;
  int idx = blockIdx.x * 4 + w;          // idx = b*N + n
  if (idx >= BB * N) return;
  int b = idx / N, n = idx - b * N;
  const bf16* xrrow  = xr + (size_t)idx * C1;
  const bf16* xlbase = xl + (size_t)b * N * C1;

  float attv[4], xrv[4], xls[4], num[4];
#pragma unroll
  for (int j = 0; j < 4; ++j) {
    int c = j * 64 + lane;
    bool valid = c < C1;
    attv[j] = valid ? ldf<BF>(att, c) : 0.f;
    xrv[j]  = valid ? bf2f(xrrow[c]) : 0.f;
  }
  // self-loop edge (src = n); PyG appends loops to every node
  {
    const bf16* row = xlbase + (size_t)n * C1;
#pragma unroll
    for (int j = 0; j < 4; ++j) {
      int c = j * 64 + lane;
      xls[j] = (c < C1) ? bf2f(row[c]) : 0.f;
    }
  }
  float t = 0.f;
#pragma unroll
  for (int j = 0; j < 4; ++j) {
    float msg = xls[j] + xrv[j];
    msg = (msg > 0.f) ? msg : NEG * msg;
    t += msg * attv[j];
  }
#pragma unroll
  for (int off = 32; off > 0; off >>= 1) t += __shfl_xor(t, off);
  float m = t, denom = 1.f;
#pragma unroll
  for (int j = 0; j < 4; ++j) num[j] = xls[j];

  int beg = rowptr[n], end = rowptr[n + 1];
  for (int p = beg; p < end; ++p) {
    int s = col[p];
    const bf16* row = xlbase + (size_t)s * C1;
    float e = 0.f;
#pragma unroll
    for (int j = 0; j < 4; ++j) {
      int c = j * 64 + lane;
      xls[j] = (c < C1) ? bf2f(row[c]) : 0.f;
      float msg = xls[j] + xrv[j];
      msg = (msg > 0.f) ? msg : NEG * msg;
      e += msg * attv[j];
    }
#pragma unroll
    for (int off = 32; off > 0; off >>= 1) e += __shfl_xor(e, off);
    float mn = fmaxf(m, e);
    float so = __expf(m - mn);
    float pe = __expf(e - mn);
    denom = denom * so + pe;
#pragma unroll
    for (int j = 0; j < 4; ++j) num[j] = num[j] * so + pe * xls[j];
    m = mn;
  }
  float invd = 1.f / denom;
  size_t base = (size_t)idx * UU_;
#pragma unroll
  for (int j = 0; j < 4; ++j) {
    int c = j * 64 + lane;
    if (c < C1) {
      float o = num[j] * invd + ldf<BF>(bg, c) + ldf<BF>(bias0, c);
      float v = 1.f / (1.f + __expf(-o));
      if (c < UU_) rs[base + c] = __float2bfloat16(v * ldf<BF>(st, base + c)); // r*state
      else         stf<BF>(uu, base + (c - UU_), v);                           // u gate in d_out
    }
  }
}

template<int BF>
__global__ __launch_bounds__(256) void k_agg2(
    const int* __restrict__ flag,
    const bf16* __restrict__ xl, const bf16* __restrict__ xr,
    const int* __restrict__ rowptr, const int* __restrict__ col,
    const void* __restrict__ att, const void* __restrict__ bg, const void* __restrict__ bias1,
    const void* __restrict__ st, void* __restrict__ out, int N) {
  if (*flag != BF) return;
  int w = threadIdx.x >> 6, lane = threadIdx.x & 63;
  int idx = blockIdx.x * 4 + w;
  if (idx >= BB * N) return;
  int b = idx / N, n = idx - b * N;
  const bf16* xrrow  = xr + (size_t)idx * C2;
  const bf16* xlbase = xl + (size_t)b * N * C2;

  float attv[2], xrv[2], xls[2], num[2];
#pragma unroll
  for (int j = 0; j < 2; ++j) {
    int c = j * 64 + lane;
    bool valid = c < C2;
    attv[j] = valid ? ldf<BF>(att, c) : 0.f;
    xrv[j]  = valid ? bf2f(xrrow[c]) : 0.f;
  }
  {
    const bf16* row = xlbase + (size_t)n * C2;
#pragma unroll
    for (int j = 0; j < 2; ++j) {
      int c = j * 64 + lane;
      xls[j] = (c < C2) ? bf2f(row[c]) : 0.f;
    }
  }
  float t = 0.f;
#pragma unroll
  for (int j = 0; j < 2; ++j) {
    float msg = xls[j] + xrv[j];
    msg = (msg > 0.f) ? msg : NEG * msg;
    t += msg * attv[j];
  }
#pragma unroll
  for (int off = 32; off > 0; off >>= 1) t += __shfl_xor(t, off);
  float m = t, denom = 1.f;
#pragma unroll
  for (int j = 0; j < 2; ++j) num[j] = xls[j];

  int beg = rowptr[n], end = rowptr[n + 1];
  for (int p = beg; p < end; ++p) {
    int s = col[p];
    const bf16* row = xlbase + (size_t)s * C2;
    float e = 0.f;
#pragma unroll
    for (int j = 0; j < 2; ++j) {
      int c = j * 64 + lane;
      xls[j] = (c < C2) ? bf2f(row[c]) : 0.f;
      float msg = xls[j] + xrv[j];
      msg = (msg > 0.f) ? msg : NEG * msg;
      e += msg * attv[j];
    }
#pragma unroll
    for (int off = 32; off > 0; off >>= 1) e += __shfl_xor(e, off);
    float mn = fmaxf(m, e);
    float so = __expf(m - mn);
    float pe = __expf(e - mn);
    denom = denom * so + pe;
#pragma unroll
    for (int j = 0; j < 2; ++j) num[j] = num[j] * so + pe * xls[j];
    m = mn;
  }
  float invd = 1.f / denom;
  size_t base = (size_t)idx * UU_;
#pragma unroll
  for (int j = 0; j < 2; ++j) {
    int c = j * 64 + lane;
    if (c < C2) {
      float o  = num[j] * invd + ldf<BF>(bg, c) + ldf<BF>(bias1, c);
      float cv = tanhf(o);
      float u  = ldf<BF>(out, base + c);   // u gate parked here by k_agg1
      float sv = ldf<BF>(st, base + c);
      stf<BF>(out, base + c, u * sv + (1.f - u) * cv);
    }
  }
}

// ---------------- launch ----------------

extern "C" void kernel_launch(void* const* d_in, const int* in_sizes, int n_in,
                              void* d_out, int out_size, void* d_ws, size_t ws_size,
                              hipStream_t stream) {
  const void* inp  = d_in[0];
  const void* st   = d_in[1];
  const int*  src  = (const int*)d_in[2];
  const int*  dst  = (const int*)d_in[3];
  const void* Wl1  = d_in[4];
  const void* bl1  = d_in[5];
  const void* Wr1  = d_in[6];
  const void* br1  = d_in[7];
  const void* att1 = d_in[8];
  const void* bg1  = d_in[9];
  const void* bias0= d_in[10];
  const void* Wl2  = d_in[11];
  const void* bl2  = d_in[12];
  const void* Wr2  = d_in[13];
  const void* br2  = d_in[14];
  const void* att2 = d_in[15];
  const void* bg2  = d_in[16];
  const void* bias1= d_in[17];

  const int N = in_sizes[0] / BB;   // 20000
  const int E = in_sizes[2];        // 160000

  // ws layout (~40.9 MB): xl1[0,16M) xr1[16M,32M) rs[32M,40M) CSR+flag
  bf16* xl1 = (bf16*)d_ws;
  bf16* xr1 = xl1 + (size_t)BB * N * C1;       // +8M bf16
  bf16* rs  = xr1 + (size_t)BB * N * C1;       // +8M bf16
  int* rowptr = (int*)(rs + (size_t)BB * N * UU_);  // +4M bf16
  int* cursor = rowptr + (N + 1);
  int* col    = cursor + N;
  int* flag   = col + E;
  bf16* xl2 = xl1;                              // layer-2 reuses dead xl1 region
  bf16* xr2 = xl1 + (size_t)BB * N * C2;

  k_detect<<<1, 64, 0, stream>>>((const uint32_t*)st, flag);

  // CSR of incoming real edges (self-loops handled in-agg)
  k_zero<<<(N + 255) / 256, 256, 0, stream>>>(cursor, N);
  k_hist<<<(E + 255) / 256, 256, 0, stream>>>(dst, E, cursor);
  k_scan<<<1, 1024, 0, stream>>>(cursor, rowptr, N, E);
  k_scatter<<<(E + 255) / 256, 256, 0, stream>>>(src, dst, E, cursor, col);

  int gx = (N + 7) / 8, ga = (BB * N + 3) / 4;
  // layer 1
  k_xform1<0><<<gx, 256, 0, stream>>>(flag, inp, st, Wl1, bl1, Wr1, br1, xl1, xr1, N);
  k_xform1<1><<<gx, 256, 0, stream>>>(flag, inp, st, Wl1, bl1, Wr1, br1, xl1, xr1, N);
  k_agg1<0><<<ga, 256, 0, stream>>>(flag, xl1, xr1, rowptr, col, att1, bg1, bias0, st, rs, d_out, N);
  k_agg1<1><<<ga, 256, 0, stream>>>(flag, xl1, xr1, rowptr, col, att1, bg1, bias0, st, rs, d_out, N);
  // layer 2
  k_xform2<0><<<gx, 256, 0, stream>>>(flag, inp, rs, Wl2, bl2, Wr2, br2, xl2, xr2, N);
  k_xform2<1><<<gx, 256, 0, stream>>>(flag, inp, rs, Wl2, bl2, Wr2, br2, xl2, xr2, N);
  k_agg2<0><<<ga, 256, 0, stream>>>(flag, xl2, xr2, rowptr, col, att2, bg2, bias1, st, d_out, N);
  k_agg2<1><<<ga, 256, 0, stream>>>(flag, xl2, xr2, rowptr, col, att2, bg2, bias1, st, d_out, N);
}

// Round 4
// 262.718 us; speedup vs baseline: 1.2091x; 1.2091x over previous
//
#include <hip/hip_runtime.h>
#include <stdint.h>

typedef __attribute__((ext_vector_type(8))) short short8;   // 8 bf16 (bit pattern)
typedef __attribute__((ext_vector_type(4))) float f32x4;

static constexpr int BB = 2, NN = 20000, UU = 100;
static constexpr int C1 = 200, C2 = 100;
static constexpr int MT = BB * NN;       // 40000 node-rows
static constexpr int MPAD = 40064;       // 313 * 128
static constexpr float NEG = 0.2f;

__device__ __forceinline__ float b2f(short s) {
  union { uint32_t u; float f; } cv; cv.u = ((uint32_t)(uint16_t)s) << 16; return cv.f;
}
__device__ __forceinline__ short f2b(float x) {             // RNE f32->bf16
  union { float f; uint32_t u; } cv; cv.f = x;
  uint32_t r = cv.u + 0x7FFFu + ((cv.u >> 16) & 1u);
  return (short)(r >> 16);
}
// element position within a 128-elem swizzled row: 16B granules XOR'd by row&7
__device__ __forceinline__ int swz(int r, int e) {
  return (((e >> 3) ^ (r & 7)) << 3) + (e & 7);
}

#define GL2LDS(gsrc, ldst)                                                          \
  __builtin_amdgcn_global_load_lds((const __attribute__((address_space(1))) void*)(gsrc), \
                                   (__attribute__((address_space(3))) void*)(ldst), 16, 0, 0)

// ---------------- CSR build ----------------

__global__ void k_zero(int* __restrict__ p, int n) {
  int i = blockIdx.x * 256 + threadIdx.x;
  if (i < n) p[i] = 0;
}

__global__ void k_hist(const int* __restrict__ dst, int E, int* __restrict__ hist) {
  int e = blockIdx.x * 256 + threadIdx.x;
  if (e < E) atomicAdd(&hist[dst[e]], 1);
}

__global__ __launch_bounds__(1024) void k_scan(int* __restrict__ histcur,
                                               int* __restrict__ rowptr, int N, int E) {
  __shared__ int part[1024];
  int t = threadIdx.x;
  int CH = (N + 1023) / 1024;
  int beg = t * CH; if (beg > N) beg = N;
  int end = beg + CH; if (end > N) end = N;
  int s = 0;
  for (int i = beg; i < end; ++i) s += histcur[i];
  part[t] = s;
  __syncthreads();
  for (int off = 1; off < 1024; off <<= 1) {
    int v = (t >= off) ? part[t - off] : 0;
    __syncthreads();
    part[t] += v;
    __syncthreads();
  }
  int base = (t == 0) ? 0 : part[t - 1];
  for (int i = beg; i < end; ++i) {
    int h = histcur[i];
    rowptr[i] = base;
    histcur[i] = base;
    base += h;
  }
  if (t == 1023) rowptr[N] = part[1023];
}

__global__ void k_scatter(const int* __restrict__ src, const int* __restrict__ dst, int E,
                          int* __restrict__ cursor, int* __restrict__ col) {
  int e = blockIdx.x * 256 + threadIdx.x;
  if (e < E) {
    int p = atomicAdd(&cursor[dst[e]], 1);
    col[p] = src[e];
  }
}

// ---------------- A / B^T builders (fp32 -> swizzled bf16) ----------------

// A1 row r: e=0 -> inp[r]; 1..100 -> state[r*100+e-1]; else 0. One thread per 8-elem granule.
__global__ void k_buildA1(const float* __restrict__ inp, const float* __restrict__ st,
                          short* __restrict__ A) {
  int t = blockIdx.x * 256 + threadIdx.x;
  if (t >= MT * 16) return;
  int r = t >> 4, g = t & 15;
  short8 v;
#pragma unroll
  for (int j = 0; j < 8; ++j) {
    int e = g * 8 + j;
    float x = 0.f;
    if (e == 0) x = inp[r];
    else if (e <= 100) x = st[(size_t)r * 100 + e - 1];
    v[j] = f2b(x);
  }
  *(short8*)(A + (size_t)r * 128 + (((g ^ (r & 7)) << 3))) = v;
}

// BT row n (0..NPAD), cols k: W[k][n'] from Wl (n<SPLIT) or Wr. Zero-padded.
__global__ void k_buildBT(const float* __restrict__ Wl, const float* __restrict__ Wr,
                          short* __restrict__ BT, int SPLIT, int NPAD) {
  int t = blockIdx.x * 256 + threadIdx.x;
  if (t >= NPAD * 16) return;
  int n = t >> 4, g = t & 15;
  short8 v;
#pragma unroll
  for (int j = 0; j < 8; ++j) {
    int k = g * 8 + j;
    float x = 0.f;
    if (k < 101 && n < 2 * SPLIT)
      x = (n < SPLIT) ? Wl[(size_t)k * SPLIT + n] : Wr[(size_t)k * SPLIT + n - SPLIT];
    v[j] = f2b(x);
  }
  *(short8*)(BT + (size_t)n * 128 + ((g ^ (n & 7)) << 3)) = v;
}

// A2 fixups: e=0 (inp) and K-pad e=101..127 (agg1 fills e=1..100 = r*state).
__global__ void k_fillA2(const float* __restrict__ inp, short* __restrict__ A) {
  int r = blockIdx.x * 256 + threadIdx.x;
  if (r >= MT) return;
  short* row = A + (size_t)r * 128;
  row[swz(r, 0)] = f2b(inp[r]);
#pragma unroll
  for (int e = 101; e < 128; ++e) row[swz(r, e)] = 0;
}

// ---------------- MFMA GEMM: X[M][NOUT] = A[M][128] @ BT^T + bias ----------------
// 128x128 tile / block, 4 waves of 64x64, single LDS stage (K=128).

template<int NOUT, int SPLIT>
__global__ __launch_bounds__(256) void k_gemm(
    const short* __restrict__ A, const short* __restrict__ BT,
    const float* __restrict__ bias_l, const float* __restrict__ bias_r,
    short* __restrict__ X) {
  __shared__ __align__(16) short As[128 * 128];
  __shared__ __align__(16) short Bs[128 * 128];
  int tid = threadIdx.x;
  int m0 = blockIdx.x * 128;
  int n0 = blockIdx.y * 128;
  {
    const short* gA = A + (size_t)m0 * 128;
    const short* gB = BT + (size_t)n0 * 128;
#pragma unroll
    for (int i = 0; i < 8; ++i) {
      GL2LDS(gA + i * 2048 + tid * 8, As + i * 2048 + tid * 8);
      GL2LDS(gB + i * 2048 + tid * 8, Bs + i * 2048 + tid * 8);
    }
  }
  __syncthreads();

  int wv = tid >> 6, lane = tid & 63;
  int m_off = (wv & 1) * 64, n_off = (wv >> 1) * 64;
  int lrow = lane & 15, lk = lane >> 4;   // frag row / k-group
  f32x4 acc[4][4];
#pragma unroll
  for (int i = 0; i < 4; ++i)
#pragma unroll
    for (int j = 0; j < 4; ++j) acc[i][j] = (f32x4){0.f, 0.f, 0.f, 0.f};

#pragma unroll
  for (int kk = 0; kk < 4; ++kk) {        // K-steps of 32
    int g = kk * 4 + lk;                  // logical 16B granule in row
    short8 a[4], b[4];
#pragma unroll
    for (int f = 0; f < 4; ++f) {
      int ra = m_off + f * 16 + lrow;
      a[f] = *(const short8*)(As + ra * 128 + ((g ^ (ra & 7)) << 3));
      int rb = n_off + f * 16 + lrow;
      b[f] = *(const short8*)(Bs + rb * 128 + ((g ^ (rb & 7)) << 3));
    }
#pragma unroll
    for (int i = 0; i < 4; ++i)
#pragma unroll
      for (int j = 0; j < 4; ++j)
        acc[i][j] = __builtin_amdgcn_mfma_f32_16x16x32_bf16(a[i], b[j], acc[i][j], 0, 0, 0);
  }

  // epilogue: C row=(lane>>4)*4+reg, col=lane&15 ; + bias ; guarded bf16 store
#pragma unroll
  for (int j = 0; j < 4; ++j) {
    int n = n0 + n_off + j * 16 + lrow;
    bool nok = n < NOUT;
    float bv = 0.f;
    if (nok) bv = (n < SPLIT) ? bias_l[n] : bias_r[n - SPLIT];
#pragma unroll
    for (int i = 0; i < 4; ++i) {
      int mb = m0 + m_off + i * 16 + lk * 4;
#pragma unroll
      for (int r = 0; r < 4; ++r) {
        int m = mb + r;
        if (nok && m < MT) X[(size_t)m * NOUT + n] = f2b(acc[i][j][r] + bv);
      }
    }
  }
}

// ---------------- GATv2 aggregation: one wave per (b,dst), online softmax ----------------

__global__ __launch_bounds__(256) void k_agg1(
    const short* __restrict__ X1, const int* __restrict__ rowptr, const int* __restrict__ col,
    const float* __restrict__ att, const float* __restrict__ bgv, const float* __restrict__ bias0,
    const float* __restrict__ st, short* __restrict__ A2, float* __restrict__ uu) {
  int w = threadIdx.x >> 6, lane = threadIdx.x & 63;
  int idx = blockIdx.x * 4 + w;           // b*NN + n
  if (idx >= MT) return;
  int b = idx / NN, n = idx - b * NN;
  const short* xrrow = X1 + (size_t)idx * 400 + 200;
  const short* xlb   = X1 + (size_t)b * NN * 400;

  float attv[4], xrv[4], xls[4], num[4];
#pragma unroll
  for (int j = 0; j < 4; ++j) {
    int c = j * 64 + lane;
    bool ok = c < C1;
    attv[j] = ok ? att[c] : 0.f;
    xrv[j]  = ok ? b2f(xrrow[c]) : 0.f;
  }
  { // self-loop (src = n)
    const short* row = xlb + (size_t)n * 400;
#pragma unroll
    for (int j = 0; j < 4; ++j) {
      int c = j * 64 + lane;
      xls[j] = (c < C1) ? b2f(row[c]) : 0.f;
    }
  }
  float t = 0.f;
#pragma unroll
  for (int j = 0; j < 4; ++j) {
    float msg = xls[j] + xrv[j];
    msg = (msg > 0.f) ? msg : NEG * msg;
    t += msg * attv[j];
  }
#pragma unroll
  for (int off = 32; off > 0; off >>= 1) t += __shfl_xor(t, off);
  float m = t, denom = 1.f;
#pragma unroll
  for (int j = 0; j < 4; ++j) num[j] = xls[j];

  int beg = rowptr[n], end = rowptr[n + 1];
  for (int p = beg; p < end; ++p) {
    int s = col[p];
    const short* row = xlb + (size_t)s * 400;
    float e = 0.f;
#pragma unroll
    for (int j = 0; j < 4; ++j) {
      int c = j * 64 + lane;
      xls[j] = (c < C1) ? b2f(row[c]) : 0.f;
      float msg = xls[j] + xrv[j];
      msg = (msg > 0.f) ? msg : NEG * msg;
      e += msg * attv[j];
    }
#pragma unroll
    for (int off = 32; off > 0; off >>= 1) e += __shfl_xor(e, off);
    float mn = fmaxf(m, e);
    float so = __expf(m - mn);
    float pe = __expf(e - mn);
    denom = denom * so + pe;
#pragma unroll
    for (int j = 0; j < 4; ++j) num[j] = num[j] * so + pe * xls[j];
    m = mn;
  }
  float invd = 1.f / denom;
  size_t base = (size_t)idx * UU;
#pragma unroll
  for (int j = 0; j < 4; ++j) {
    int c = j * 64 + lane;
    if (c < C1) {
      float o = num[j] * invd + bgv[c] + bias0[c];
      float v = 1.f / (1.f + __expf(-o));
      if (c < UU) {  // r*state -> A2 element e=c+1, swizzled
        int e = c + 1;
        A2[(size_t)idx * 128 + swz(idx, e)] = f2b(v * st[base + c]);
      } else {
        uu[base + (c - UU)] = v;           // u gate parked in d_out (fp32)
      }
    }
  }
}

__global__ __launch_bounds__(256) void k_agg2(
    const short* __restrict__ X2, const int* __restrict__ rowptr, const int* __restrict__ col,
    const float* __restrict__ att, const float* __restrict__ bgv, const float* __restrict__ bias1,
    const float* __restrict__ st, float* __restrict__ out) {
  int w = threadIdx.x >> 6, lane = threadIdx.x & 63;
  int idx = blockIdx.x * 4 + w;
  if (idx >= MT) return;
  int b = idx / NN, n = idx - b * NN;
  const short* xrrow = X2 + (size_t)idx * 200 + 100;
  const short* xlb   = X2 + (size_t)b * NN * 200;

  float attv[2], xrv[2], xls[2], num[2];
#pragma unroll
  for (int j = 0; j < 2; ++j) {
    int c = j * 64 + lane;
    bool ok = c < C2;
    attv[j] = ok ? att[c] : 0.f;
    xrv[j]  = ok ? b2f(xrrow[c]) : 0.f;
  }
  {
    const short* row = xlb + (size_t)n * 200;
#pragma unroll
    for (int j = 0; j < 2; ++j) {
      int c = j * 64 + lane;
      xls[j] = (c < C2) ? b2f(row[c]) : 0.f;
    }
  }
  float t = 0.f;
#pragma unroll
  for (int j = 0; j < 2; ++j) {
    float msg = xls[j] + xrv[j];
    msg = (msg > 0.f) ? msg : NEG * msg;
    t += msg * attv[j];
  }
#pragma unroll
  for (int off = 32; off > 0; off >>= 1) t += __shfl_xor(t, off);
  float m = t, denom = 1.f;
#pragma unroll
  for (int j = 0; j < 2; ++j) num[j] = xls[j];

  int beg = rowptr[n], end = rowptr[n + 1];
  for (int p = beg; p < end; ++p) {
    int s = col[p];
    const short* row = xlb + (size_t)s * 200;
    float e = 0.f;
#pragma unroll
    for (int j = 0; j < 2; ++j) {
      int c = j * 64 + lane;
      xls[j] = (c < C2) ? b2f(row[c]) : 0.f;
      float msg = xls[j] + xrv[j];
      msg = (msg > 0.f) ? msg : NEG * msg;
      e += msg * attv[j];
    }
#pragma unroll
    for (int off = 32; off > 0; off >>= 1) e += __shfl_xor(e, off);
    float mn = fmaxf(m, e);
    float so = __expf(m - mn);
    float pe = __expf(e - mn);
    denom = denom * so + pe;
#pragma unroll
    for (int j = 0; j < 2; ++j) num[j] = num[j] * so + pe * xls[j];
    m = mn;
  }
  float invd = 1.f / denom;
  size_t base = (size_t)idx * UU;
#pragma unroll
  for (int j = 0; j < 2; ++j) {
    int c = j * 64 + lane;
    if (c < C2) {
      float o  = num[j] * invd + bgv[c] + bias1[c];
      float cv = tanhf(o);
      float u  = out[base + c];            // u gate parked here by k_agg1
      float sv = st[base + c];
      out[base + c] = u * sv + (1.f - u) * cv;
    }
  }
}

// ---------------- launch ----------------

extern "C" void kernel_launch(void* const* d_in, const int* in_sizes, int n_in,
                              void* d_out, int out_size, void* d_ws, size_t ws_size,
                              hipStream_t stream) {
  const float* inp  = (const float*)d_in[0];
  const float* st   = (const float*)d_in[1];
  const int*   src  = (const int*)d_in[2];
  const int*   dst  = (const int*)d_in[3];
  const float* Wl1  = (const float*)d_in[4];
  const float* bl1  = (const float*)d_in[5];
  const float* Wr1  = (const float*)d_in[6];
  const float* br1  = (const float*)d_in[7];
  const float* att1 = (const float*)d_in[8];
  const float* bg1  = (const float*)d_in[9];
  const float* bias0= (const float*)d_in[10];
  const float* Wl2  = (const float*)d_in[11];
  const float* bl2  = (const float*)d_in[12];
  const float* Wr2  = (const float*)d_in[13];
  const float* br2  = (const float*)d_in[14];
  const float* att2 = (const float*)d_in[15];
  const float* bg2  = (const float*)d_in[16];
  const float* bias1= (const float*)d_in[17];

  const int N = NN;
  const int E = in_sizes[2];   // 160000

  // ws (~43.3 MB): X1[32MB] | A[10.26MB] | BT1 | BT2 | CSR.  X2 aliases X1 front.
  short* X1  = (short*)d_ws;                       // 40000*400
  short* X2  = X1;                                 // 40000*200 (X1 dead by then)
  short* Aws = X1 + (size_t)MT * 400;              // MPAD*128
  short* BT1 = Aws + (size_t)MPAD * 128;           // 512*128
  short* BT2 = BT1 + 512 * 128;                    // 256*128
  int* rowptr = (int*)(BT2 + 256 * 128);
  int* cursor = rowptr + (N + 1);
  int* col    = cursor + N;

  // CSR of incoming real edges (self-loops handled in-agg)
  k_zero<<<(N + 255) / 256, 256, 0, stream>>>(cursor, N);
  k_hist<<<(E + 255) / 256, 256, 0, stream>>>(dst, E, cursor);
  k_scan<<<1, 1024, 0, stream>>>(cursor, rowptr, N, E);
  k_scatter<<<(E + 255) / 256, 256, 0, stream>>>(src, dst, E, cursor, col);

  // layer 1: A1 = [inp|state] ; X1 = A1 @ [Wl1|Wr1] + [bl1|br1]
  k_buildA1<<<(MT * 16 + 255) / 256, 256, 0, stream>>>(inp, st, Aws);
  k_buildBT<<<(512 * 16 + 255) / 256, 256, 0, stream>>>(Wl1, Wr1, BT1, C1, 512);
  k_buildBT<<<(256 * 16 + 255) / 256, 256, 0, stream>>>(Wl2, Wr2, BT2, C2, 256);
  {
    dim3 g(MPAD / 128, 4);
    k_gemm<400, 200><<<g, 256, 0, stream>>>(Aws, BT1, bl1, br1, X1);
  }
  k_agg1<<<(MT + 3) / 4, 256, 0, stream>>>(X1, rowptr, col, att1, bg1, bias0, st,
                                           Aws, (float*)d_out);
  // layer 2: A2 = [inp | r*state] (agg1 wrote r*state; fill inp + K-pad)
  k_fillA2<<<(MT + 255) / 256, 256, 0, stream>>>(inp, Aws);
  {
    dim3 g(MPAD / 128, 2);
    k_gemm<200, 100><<<g, 256, 0, stream>>>(Aws, BT2, bl2, br2, X2);
  }
  k_agg2<<<(MT + 3) / 4, 256, 0, stream>>>(X2, rowptr, col, att2, bg2, bias1, st,
                                           (float*)d_out);
}

// Round 5
// 252.356 us; speedup vs baseline: 1.2588x; 1.0411x over previous
//
#include <hip/hip_runtime.h>
#include <stdint.h>

typedef __attribute__((ext_vector_type(8))) short short8;   // 8 bf16 (bit pattern)
typedef __attribute__((ext_vector_type(4))) short short4v;  // 4 bf16
typedef __attribute__((ext_vector_type(2))) short short2v;  // 2 bf16
typedef __attribute__((ext_vector_type(4))) float f32x4;
typedef __attribute__((ext_vector_type(2))) float f32x2;

static constexpr int BB = 2, NN = 20000, UU = 100;
static constexpr int C1 = 200, C2 = 100;
static constexpr int MT = BB * NN;       // 40000 node-rows
static constexpr int MPAD = 40064;       // 313 * 128
static constexpr float NEG = 0.2f;
static constexpr float THR = 20.f;       // defer-max threshold (fp32 headroom)

__device__ __forceinline__ float b2f(short s) {
  union { uint32_t u; float f; } cv; cv.u = ((uint32_t)(uint16_t)s) << 16; return cv.f;
}
__device__ __forceinline__ short f2b(float x) {             // RNE f32->bf16
  union { float f; uint32_t u; } cv; cv.f = x;
  uint32_t r = cv.u + 0x7FFFu + ((cv.u >> 16) & 1u);
  return (short)(r >> 16);
}
// element position within a 128-elem swizzled row: 16B granules XOR'd by row&7
__device__ __forceinline__ int swz(int r, int e) {
  return (((e >> 3) ^ (r & 7)) << 3) + (e & 7);
}

#define GL2LDS(gsrc, ldst)                                                          \
  __builtin_amdgcn_global_load_lds((const __attribute__((address_space(1))) void*)(gsrc), \
                                   (__attribute__((address_space(3))) void*)(ldst), 16, 0, 0)

// ---------------- CSR build ----------------

__global__ void k_zero(int* __restrict__ p, int n) {
  int i = blockIdx.x * 256 + threadIdx.x;
  if (i < n) p[i] = 0;
}

__global__ void k_hist(const int* __restrict__ dst, int E, int* __restrict__ hist) {
  int e = blockIdx.x * 256 + threadIdx.x;
  if (e < E) atomicAdd(&hist[dst[e]], 1);
}

__global__ __launch_bounds__(1024) void k_scan(int* __restrict__ histcur,
                                               int* __restrict__ rowptr, int N, int E) {
  __shared__ int part[1024];
  int t = threadIdx.x;
  int CH = (N + 1023) / 1024;
  int beg = t * CH; if (beg > N) beg = N;
  int end = beg + CH; if (end > N) end = N;
  int s = 0;
  for (int i = beg; i < end; ++i) s += histcur[i];
  part[t] = s;
  __syncthreads();
  for (int off = 1; off < 1024; off <<= 1) {
    int v = (t >= off) ? part[t - off] : 0;
    __syncthreads();
    part[t] += v;
    __syncthreads();
  }
  int base = (t == 0) ? 0 : part[t - 1];
  for (int i = beg; i < end; ++i) {
    int h = histcur[i];
    rowptr[i] = base;
    histcur[i] = base;
    base += h;
  }
  if (t == 1023) rowptr[N] = part[1023];
}

__global__ void k_scatter(const int* __restrict__ src, const int* __restrict__ dst, int E,
                          int* __restrict__ cursor, int* __restrict__ col) {
  int e = blockIdx.x * 256 + threadIdx.x;
  if (e < E) {
    int p = atomicAdd(&cursor[dst[e]], 1);
    col[p] = src[e];
  }
}

// ---------------- A / B^T builders (fp32 -> swizzled bf16) ----------------

// A1 row r: e=0 -> inp[r]; 1..100 -> state[r*100+e-1]; else 0.
__global__ void k_buildA1(const float* __restrict__ inp, const float* __restrict__ st,
                          short* __restrict__ A) {
  int t = blockIdx.x * 256 + threadIdx.x;
  if (t >= MT * 16) return;
  int r = t >> 4, g = t & 15;
  short8 v;
#pragma unroll
  for (int j = 0; j < 8; ++j) {
    int e = g * 8 + j;
    float x = 0.f;
    if (e == 0) x = inp[r];
    else if (e <= 100) x = st[(size_t)r * 100 + e - 1];
    v[j] = f2b(x);
  }
  *(short8*)(A + (size_t)r * 128 + (((g ^ (r & 7)) << 3))) = v;
}

// BT row n, cols k. rot=0: k<101 -> W[k] (layer 1).
// rot=1 (layer 2, state-first A2 layout): k<100 -> W[k+1]; k==100 -> W[0].
__global__ void k_buildBT(const float* __restrict__ Wl, const float* __restrict__ Wr,
                          short* __restrict__ BT, int SPLIT, int NPAD, int rot) {
  int t = blockIdx.x * 256 + threadIdx.x;
  if (t >= NPAD * 16) return;
  int n = t >> 4, g = t & 15;
  short8 v;
#pragma unroll
  for (int j = 0; j < 8; ++j) {
    int k = g * 8 + j;
    int ksrc = rot ? (k < 100 ? k + 1 : (k == 100 ? 0 : -1)) : (k < 101 ? k : -1);
    float x = 0.f;
    if (ksrc >= 0 && n < 2 * SPLIT)
      x = (n < SPLIT) ? Wl[(size_t)ksrc * SPLIT + n] : Wr[(size_t)ksrc * SPLIT + n - SPLIT];
    v[j] = f2b(x);
  }
  *(short8*)(BT + (size_t)n * 128 + ((g ^ (n & 7)) << 3)) = v;
}

// A2 fixups: position 100 = inp, 101..127 = 0 (agg1 fills 0..99 = r*state).
__global__ void k_fillA2(const float* __restrict__ inp, short* __restrict__ A) {
  int r = blockIdx.x * 256 + threadIdx.x;
  if (r >= MT) return;
  short* row = A + (size_t)r * 128;
  row[swz(r, 100)] = f2b(inp[r]);
#pragma unroll
  for (int e = 101; e < 128; ++e) row[swz(r, e)] = 0;
}

// ---------------- MFMA GEMM: X[M][NOUT] = A[M][128] @ BT^T + bias ----------------

template<int NOUT, int SPLIT>
__global__ __launch_bounds__(256) void k_gemm(
    const short* __restrict__ A, const short* __restrict__ BT,
    const float* __restrict__ bias_l, const float* __restrict__ bias_r,
    short* __restrict__ X) {
  __shared__ __align__(16) short As[128 * 128];
  __shared__ __align__(16) short Bs[128 * 128];
  int tid = threadIdx.x;
  int m0 = blockIdx.x * 128;
  int n0 = blockIdx.y * 128;
  {
    const short* gA = A + (size_t)m0 * 128;
    const short* gB = BT + (size_t)n0 * 128;
#pragma unroll
    for (int i = 0; i < 8; ++i) {
      GL2LDS(gA + i * 2048 + tid * 8, As + i * 2048 + tid * 8);
      GL2LDS(gB + i * 2048 + tid * 8, Bs + i * 2048 + tid * 8);
    }
  }
  __syncthreads();

  int wv = tid >> 6, lane = tid & 63;
  int m_off = (wv & 1) * 64, n_off = (wv >> 1) * 64;
  int lrow = lane & 15, lk = lane >> 4;
  f32x4 acc[4][4];
#pragma unroll
  for (int i = 0; i < 4; ++i)
#pragma unroll
    for (int j = 0; j < 4; ++j) acc[i][j] = (f32x4){0.f, 0.f, 0.f, 0.f};

#pragma unroll
  for (int kk = 0; kk < 4; ++kk) {
    int g = kk * 4 + lk;
    short8 a[4], b[4];
#pragma unroll
    for (int f = 0; f < 4; ++f) {
      int ra = m_off + f * 16 + lrow;
      a[f] = *(const short8*)(As + ra * 128 + ((g ^ (ra & 7)) << 3));
      int rb = n_off + f * 16 + lrow;
      b[f] = *(const short8*)(Bs + rb * 128 + ((g ^ (rb & 7)) << 3));
    }
#pragma unroll
    for (int i = 0; i < 4; ++i)
#pragma unroll
      for (int j = 0; j < 4; ++j)
        acc[i][j] = __builtin_amdgcn_mfma_f32_16x16x32_bf16(a[i], b[j], acc[i][j], 0, 0, 0);
  }

#pragma unroll
  for (int j = 0; j < 4; ++j) {
    int n = n0 + n_off + j * 16 + lrow;
    bool nok = n < NOUT;
    float bv = 0.f;
    if (nok) bv = (n < SPLIT) ? bias_l[n] : bias_r[n - SPLIT];
#pragma unroll
    for (int i = 0; i < 4; ++i) {
      int mb = m0 + m_off + i * 16 + lk * 4;
#pragma unroll
      for (int r = 0; r < 4; ++r) {
        int m = mb + r;
        if (nok && m < MT) X[(size_t)m * NOUT + n] = f2b(acc[i][j][r] + bv);
      }
    }
  }
}

// ---------------- GATv2 aggregation: one wave per (b,dst), online softmax ----------------
// Lane l owns channels 4l..4l+3 (agg1) / 2l,2l+1 (agg2); lanes >= 50 carry att=0.

__global__ __launch_bounds__(256) void k_agg1(
    const short* __restrict__ X1, const int* __restrict__ rowptr, const int* __restrict__ col,
    const float* __restrict__ att, const float* __restrict__ bgv, const float* __restrict__ bias0,
    const float* __restrict__ st, short* __restrict__ A2, float* __restrict__ uu) {
  int w = threadIdx.x >> 6, lane = threadIdx.x & 63;
  int idx = blockIdx.x * 4 + w;           // b*NN + n
  if (idx >= MT) return;
  int b = idx / NN, n = idx - b * NN;
  int c = lane * 4;
  const short* xlb = X1 + (size_t)b * NN * 400;

  f32x4 attv = (f32x4){0.f, 0.f, 0.f, 0.f};
  f32x4 xrv  = (f32x4){0.f, 0.f, 0.f, 0.f};
  if (lane < 50) {
    attv = *(const f32x4*)(att + c);
    short4v x4 = *(const short4v*)(X1 + (size_t)idx * 400 + 200 + c);
#pragma unroll
    for (int q = 0; q < 4; ++q) xrv[q] = b2f(x4[q]);
  }
  float xls[4];
  { // self-loop (src = n)
    short4v v = *(const short4v*)(xlb + (size_t)n * 400 + c);
#pragma unroll
    for (int q = 0; q < 4; ++q) xls[q] = b2f(v[q]);
  }
  float t = 0.f;
#pragma unroll
  for (int q = 0; q < 4; ++q) {
    float msg = xls[q] + xrv[q];
    msg = (msg > 0.f) ? msg : NEG * msg;
    t = fmaf(msg, attv[q], t);
  }
#pragma unroll
  for (int off = 32; off > 0; off >>= 1) t += __shfl_xor(t, off);
  float m = t, denom = 1.f;
  float num[4];
#pragma unroll
  for (int q = 0; q < 4; ++q) num[q] = xls[q];

  int beg = rowptr[n], end = rowptr[n + 1];
  for (int p = beg; p < end; ++p) {
    int s = col[p];
    short4v v = *(const short4v*)(xlb + (size_t)s * 400 + c);
    float e = 0.f;
#pragma unroll
    for (int q = 0; q < 4; ++q) {
      xls[q] = b2f(v[q]);
      float msg = xls[q] + xrv[q];
      msg = (msg > 0.f) ? msg : NEG * msg;
      e = fmaf(msg, attv[q], e);
    }
#pragma unroll
    for (int off = 32; off > 0; off >>= 1) e += __shfl_xor(e, off);
    float d = e - m;
    if (d > THR) {                        // rare, wave-uniform rescale
      float so = __expf(-d);
      denom *= so;
#pragma unroll
      for (int q = 0; q < 4; ++q) num[q] *= so;
      m = e; d = 0.f;
    }
    float pe = __expf(d);
    denom += pe;
#pragma unroll
    for (int q = 0; q < 4; ++q) num[q] = fmaf(pe, xls[q], num[q]);
  }
  float invd = 1.f / denom;
  if (lane < 50) {
    f32x4 bb = *(const f32x4*)(bgv + c);
    f32x4 b2 = *(const f32x4*)(bias0 + c);
    float vq[4];
#pragma unroll
    for (int q = 0; q < 4; ++q) {
      float o = fmaf(num[q], invd, bb[q] + b2[q]);
      vq[q] = 1.f / (1.f + __expf(-o));
    }
    size_t base = (size_t)idx * UU;
    if (lane < 25) {                      // c<100: r*state -> A2 position c (state-first)
      f32x4 sv = *(const f32x4*)(st + base + c);
      short4v wv;
#pragma unroll
      for (int q = 0; q < 4; ++q) wv[q] = f2b(vq[q] * sv[q]);
      *(short4v*)(A2 + (size_t)idx * 128 + (((c >> 3) ^ (idx & 7)) << 3) + (c & 7)) = wv;
    } else {                              // c in [100,200): u gate (fp32, parked in d_out)
      *(f32x4*)(uu + base + (c - 100)) = (f32x4){vq[0], vq[1], vq[2], vq[3]};
    }
  }
}

__global__ __launch_bounds__(256) void k_agg2(
    const short* __restrict__ X2, const int* __restrict__ rowptr, const int* __restrict__ col,
    const float* __restrict__ att, const float* __restrict__ bgv, const float* __restrict__ bias1,
    const float* __restrict__ st, float* __restrict__ out) {
  int w = threadIdx.x >> 6, lane = threadIdx.x & 63;
  int idx = blockIdx.x * 4 + w;
  if (idx >= MT) return;
  int b = idx / NN, n = idx - b * NN;
  int c = lane * 2;
  const short* xlb = X2 + (size_t)b * NN * 200;

  f32x2 attv = (f32x2){0.f, 0.f};
  f32x2 xrv  = (f32x2){0.f, 0.f};
  if (lane < 50) {
    attv = *(const f32x2*)(att + c);
    short2v x2 = *(const short2v*)(X2 + (size_t)idx * 200 + 100 + c);
#pragma unroll
    for (int q = 0; q < 2; ++q) xrv[q] = b2f(x2[q]);
  }
  float xls[2];
  {
    short2v v = *(const short2v*)(xlb + (size_t)n * 200 + c);
#pragma unroll
    for (int q = 0; q < 2; ++q) xls[q] = b2f(v[q]);
  }
  float t = 0.f;
#pragma unroll
  for (int q = 0; q < 2; ++q) {
    float msg = xls[q] + xrv[q];
    msg = (msg > 0.f) ? msg : NEG * msg;
    t = fmaf(msg, attv[q], t);
  }
#pragma unroll
  for (int off = 32; off > 0; off >>= 1) t += __shfl_xor(t, off);
  float m = t, denom = 1.f;
  float num[2];
#pragma unroll
  for (int q = 0; q < 2; ++q) num[q] = xls[q];

  int beg = rowptr[n], end = rowptr[n + 1];
  for (int p = beg; p < end; ++p) {
    int s = col[p];
    short2v v = *(const short2v*)(xlb + (size_t)s * 200 + c);
    float e = 0.f;
#pragma unroll
    for (int q = 0; q < 2; ++q) {
      xls[q] = b2f(v[q]);
      float msg = xls[q] + xrv[q];
      msg = (msg > 0.f) ? msg : NEG * msg;
      e = fmaf(msg, attv[q], e);
    }
#pragma unroll
    for (int off = 32; off > 0; off >>= 1) e += __shfl_xor(e, off);
    float d = e - m;
    if (d > THR) {
      float so = __expf(-d);
      denom *= so;
#pragma unroll
      for (int q = 0; q < 2; ++q) num[q] *= so;
      m = e; d = 0.f;
    }
    float pe = __expf(d);
    denom += pe;
#pragma unroll
    for (int q = 0; q < 2; ++q) num[q] = fmaf(pe, xls[q], num[q]);
  }
  float invd = 1.f / denom;
  if (lane < 50) {
    f32x2 bb = *(const f32x2*)(bgv + c);
    f32x2 b2 = *(const f32x2*)(bias1 + c);
    size_t base = (size_t)idx * UU;
    f32x2 uv = *(const f32x2*)(out + base + c);   // u gate parked by k_agg1
    f32x2 sv = *(const f32x2*)(st + base + c);
    f32x2 res;
#pragma unroll
    for (int q = 0; q < 2; ++q) {
      float o  = fmaf(num[q], invd, bb[q] + b2[q]);
      float cv = tanhf(o);
      res[q] = uv[q] * sv[q] + (1.f - uv[q]) * cv;
    }
    *(f32x2*)(out + base + c) = res;
  }
}

// ---------------- launch ----------------

extern "C" void kernel_launch(void* const* d_in, const int* in_sizes, int n_in,
                              void* d_out, int out_size, void* d_ws, size_t ws_size,
                              hipStream_t stream) {
  const float* inp  = (const float*)d_in[0];
  const float* st   = (const float*)d_in[1];
  const int*   src  = (const int*)d_in[2];
  const int*   dst  = (const int*)d_in[3];
  const float* Wl1  = (const float*)d_in[4];
  const float* bl1  = (const float*)d_in[5];
  const float* Wr1  = (const float*)d_in[6];
  const float* br1  = (const float*)d_in[7];
  const float* att1 = (const float*)d_in[8];
  const float* bg1  = (const float*)d_in[9];
  const float* bias0= (const float*)d_in[10];
  const float* Wl2  = (const float*)d_in[11];
  const float* bl2  = (const float*)d_in[12];
  const float* Wr2  = (const float*)d_in[13];
  const float* br2  = (const float*)d_in[14];
  const float* att2 = (const float*)d_in[15];
  const float* bg2  = (const float*)d_in[16];
  const float* bias1= (const float*)d_in[17];

  const int N = NN;
  const int E = in_sizes[2];   // 160000

  // ws (~43.3 MB): X1[32MB] | A[10.26MB] | BT1 | BT2 | CSR.  X2 aliases X1 front.
  short* X1  = (short*)d_ws;                       // 40000*400
  short* X2  = X1;                                 // 40000*200 (X1 dead by then)
  short* Aws = X1 + (size_t)MT * 400;              // MPAD*128
  short* BT1 = Aws + (size_t)MPAD * 128;           // 512*128
  short* BT2 = BT1 + 512 * 128;                    // 256*128
  int* rowptr = (int*)(BT2 + 256 * 128);
  int* cursor = rowptr + (N + 1);
  int* col    = cursor + N;

  // CSR of incoming real edges (self-loops handled in-agg)
  k_zero<<<(N + 255) / 256, 256, 0, stream>>>(cursor, N);
  k_hist<<<(E + 255) / 256, 256, 0, stream>>>(dst, E, cursor);
  k_scan<<<1, 1024, 0, stream>>>(cursor, rowptr, N, E);
  k_scatter<<<(E + 255) / 256, 256, 0, stream>>>(src, dst, E, cursor, col);

  // layer 1: A1 = [inp|state] ; X1 = A1 @ [Wl1|Wr1] + [bl1|br1]
  k_buildA1<<<(MT * 16 + 255) / 256, 256, 0, stream>>>(inp, st, Aws);
  k_buildBT<<<(512 * 16 + 255) / 256, 256, 0, stream>>>(Wl1, Wr1, BT1, C1, 512, 0);
  k_buildBT<<<(256 * 16 + 255) / 256, 256, 0, stream>>>(Wl2, Wr2, BT2, C2, 256, 1);
  {
    dim3 g(MPAD / 128, 4);
    k_gemm<400, 200><<<g, 256, 0, stream>>>(Aws, BT1, bl1, br1, X1);
  }
  k_agg1<<<(MT + 3) / 4, 256, 0, stream>>>(X1, rowptr, col, att1, bg1, bias0, st,
                                           Aws, (float*)d_out);
  // layer 2: A2 = [r*state | inp] (state-first; agg1 wrote r*state; fill inp + pad)
  k_fillA2<<<(MT + 255) / 256, 256, 0, stream>>>(inp, Aws);
  {
    dim3 g(MPAD / 128, 2);
    k_gemm<200, 100><<<g, 256, 0, stream>>>(Aws, BT2, bl2, br2, X2);
  }
  k_agg2<<<(MT + 3) / 4, 256, 0, stream>>>(X2, rowptr, col, att2, bg2, bias1, st,
                                           (float*)d_out);
}

// Round 6
// 205.114 us; speedup vs baseline: 1.5487x; 1.2303x over previous
//
#include <hip/hip_runtime.h>
#include <stdint.h>

typedef __attribute__((ext_vector_type(8))) short short8;   // 8 bf16 (bit pattern)
typedef __attribute__((ext_vector_type(4))) short short4v;  // 4 bf16
typedef __attribute__((ext_vector_type(4))) float f32x4;
typedef __attribute__((ext_vector_type(2))) float f32x2;

static constexpr int BB = 2, NN = 20000, UU = 100;
static constexpr int C1 = 200, C2 = 100;
static constexpr int MT = BB * NN;       // 40000 node-rows
static constexpr int MPAD = 40064;       // 313 * 128
static constexpr float NEG = 0.2f;
static constexpr float THR = 20.f;       // defer-max threshold (fp32 headroom)

__device__ __forceinline__ float b2f(short s) {
  union { uint32_t u; float f; } cv; cv.u = ((uint32_t)(uint16_t)s) << 16; return cv.f;
}
__device__ __forceinline__ short f2b(float x) {             // RNE f32->bf16
  union { float f; uint32_t u; } cv; cv.f = x;
  uint32_t r = cv.u + 0x7FFFu + ((cv.u >> 16) & 1u);
  return (short)(r >> 16);
}
// element position within a 128-elem swizzled row: 16B granules XOR'd by row&7
__device__ __forceinline__ int swz(int r, int e) {
  return (((e >> 3) ^ (r & 7)) << 3) + (e & 7);
}
// batch-interleaved X row: m = b*NN+n -> 2n+b (adjacent batches)
__device__ __forceinline__ int ilv(int m) {
  return (m < NN) ? 2 * m : 2 * (m - NN) + 1;
}

#define GL2LDS(gsrc, ldst)                                                          \
  __builtin_amdgcn_global_load_lds((const __attribute__((address_space(1))) void*)(gsrc), \
                                   (__attribute__((address_space(3))) void*)(ldst), 16, 0, 0)

// ---------------- CSR build ----------------

__global__ void k_zero(int* __restrict__ p, int n) {
  int i = blockIdx.x * 256 + threadIdx.x;
  if (i < n) p[i] = 0;
}

__global__ void k_hist(const int* __restrict__ dst, int E, int* __restrict__ hist) {
  int e = blockIdx.x * 256 + threadIdx.x;
  if (e < E) atomicAdd(&hist[dst[e]], 1);
}

__global__ __launch_bounds__(1024) void k_scan(int* __restrict__ histcur,
                                               int* __restrict__ rowptr, int N, int E) {
  __shared__ int part[1024];
  int t = threadIdx.x;
  int CH = (N + 1023) / 1024;
  int beg = t * CH; if (beg > N) beg = N;
  int end = beg + CH; if (end > N) end = N;
  int s = 0;
  for (int i = beg; i < end; ++i) s += histcur[i];
  part[t] = s;
  __syncthreads();
  for (int off = 1; off < 1024; off <<= 1) {
    int v = (t >= off) ? part[t - off] : 0;
    __syncthreads();
    part[t] += v;
    __syncthreads();
  }
  int base = (t == 0) ? 0 : part[t - 1];
  for (int i = beg; i < end; ++i) {
    int h = histcur[i];
    rowptr[i] = base;
    histcur[i] = base;
    base += h;
  }
  if (t == 1023) rowptr[N] = part[1023];
}

__global__ void k_scatter(const int* __restrict__ src, const int* __restrict__ dst, int E,
                          int* __restrict__ cursor, int* __restrict__ col) {
  int e = blockIdx.x * 256 + threadIdx.x;
  if (e < E) {
    int p = atomicAdd(&cursor[dst[e]], 1);
    col[p] = src[e];
  }
}

// ---------------- A / B^T builders (fp32 -> swizzled bf16) ----------------

__global__ void k_buildA1(const float* __restrict__ inp, const float* __restrict__ st,
                          short* __restrict__ A) {
  int t = blockIdx.x * 256 + threadIdx.x;
  if (t >= MT * 16) return;
  int r = t >> 4, g = t & 15;
  short8 v;
#pragma unroll
  for (int j = 0; j < 8; ++j) {
    int e = g * 8 + j;
    float x = 0.f;
    if (e == 0) x = inp[r];
    else if (e <= 100) x = st[(size_t)r * 100 + e - 1];
    v[j] = f2b(x);
  }
  *(short8*)(A + (size_t)r * 128 + (((g ^ (r & 7)) << 3))) = v;
}

// BT row n, cols k. rot=0: k<101 -> W[k]. rot=1 (state-first A2): k<100 -> W[k+1]; k==100 -> W[0].
__global__ void k_buildBT(const float* __restrict__ Wl, const float* __restrict__ Wr,
                          short* __restrict__ BT, int SPLIT, int NPAD, int rot) {
  int t = blockIdx.x * 256 + threadIdx.x;
  if (t >= NPAD * 16) return;
  int n = t >> 4, g = t & 15;
  short8 v;
#pragma unroll
  for (int j = 0; j < 8; ++j) {
    int k = g * 8 + j;
    int ksrc = rot ? (k < 100 ? k + 1 : (k == 100 ? 0 : -1)) : (k < 101 ? k : -1);
    float x = 0.f;
    if (ksrc >= 0 && n < 2 * SPLIT)
      x = (n < SPLIT) ? Wl[(size_t)ksrc * SPLIT + n] : Wr[(size_t)ksrc * SPLIT + n - SPLIT];
    v[j] = f2b(x);
  }
  *(short8*)(BT + (size_t)n * 128 + ((g ^ (n & 7)) << 3)) = v;
}

// A2 fixups: position 100 = inp, 101..127 = 0 (agg1 fills 0..99 = r*state).
__global__ void k_fillA2(const float* __restrict__ inp, short* __restrict__ A) {
  int r = blockIdx.x * 256 + threadIdx.x;
  if (r >= MT) return;
  short* row = A + (size_t)r * 128;
  row[swz(r, 100)] = f2b(inp[r]);
#pragma unroll
  for (int e = 101; e < 128; ++e) row[swz(r, e)] = 0;
}

// ---------------- MFMA GEMM: X[ilv(M)][NOUT] = A[M][128] @ BT^T + bias ----------------

template<int NOUT, int SPLIT>
__global__ __launch_bounds__(256) void k_gemm(
    const short* __restrict__ A, const short* __restrict__ BT,
    const float* __restrict__ bias_l, const float* __restrict__ bias_r,
    short* __restrict__ X) {
  __shared__ __align__(16) short As[128 * 128];
  __shared__ __align__(16) short Bs[128 * 128];
  int tid = threadIdx.x;
  int m0 = blockIdx.x * 128;
  int n0 = blockIdx.y * 128;
  {
    const short* gA = A + (size_t)m0 * 128;
    const short* gB = BT + (size_t)n0 * 128;
#pragma unroll
    for (int i = 0; i < 8; ++i) {
      GL2LDS(gA + i * 2048 + tid * 8, As + i * 2048 + tid * 8);
      GL2LDS(gB + i * 2048 + tid * 8, Bs + i * 2048 + tid * 8);
    }
  }
  __syncthreads();

  int wv = tid >> 6, lane = tid & 63;
  int m_off = (wv & 1) * 64, n_off = (wv >> 1) * 64;
  int lrow = lane & 15, lk = lane >> 4;
  f32x4 acc[4][4];
#pragma unroll
  for (int i = 0; i < 4; ++i)
#pragma unroll
    for (int j = 0; j < 4; ++j) acc[i][j] = (f32x4){0.f, 0.f, 0.f, 0.f};

#pragma unroll
  for (int kk = 0; kk < 4; ++kk) {
    int g = kk * 4 + lk;
    short8 a[4], b[4];
#pragma unroll
    for (int f = 0; f < 4; ++f) {
      int ra = m_off + f * 16 + lrow;
      a[f] = *(const short8*)(As + ra * 128 + ((g ^ (ra & 7)) << 3));
      int rb = n_off + f * 16 + lrow;
      b[f] = *(const short8*)(Bs + rb * 128 + ((g ^ (rb & 7)) << 3));
    }
#pragma unroll
    for (int i = 0; i < 4; ++i)
#pragma unroll
      for (int j = 0; j < 4; ++j)
        acc[i][j] = __builtin_amdgcn_mfma_f32_16x16x32_bf16(a[i], b[j], acc[i][j], 0, 0, 0);
  }

#pragma unroll
  for (int j = 0; j < 4; ++j) {
    int n = n0 + n_off + j * 16 + lrow;
    bool nok = n < NOUT;
    float bv = 0.f;
    if (nok) bv = (n < SPLIT) ? bias_l[n] : bias_r[n - SPLIT];
#pragma unroll
    for (int i = 0; i < 4; ++i) {
      int mb = m0 + m_off + i * 16 + lk * 4;
#pragma unroll
      for (int r = 0; r < 4; ++r) {
        int m = mb + r;
        if (nok && m < MT) X[(size_t)ilv(m) * NOUT + n] = f2b(acc[i][j][r] + bv);
      }
    }
  }
}

// ---------------- GATv2 aggregation ----------------
// One wave per dst; lanes 0-31 = batch 0, 32-63 = batch 1. Lane owns 8 (agg1) /
// 4 (agg2) channels; lanes ll>=25 clamp to lane 24's address with att=0.
// Edge loop unrolled x2; col pre-staged in registers, broadcast via __shfl.

__global__ __launch_bounds__(256) void k_agg1(
    const short* __restrict__ X1, const int* __restrict__ rowptr, const int* __restrict__ col,
    const float* __restrict__ att, const float* __restrict__ bgv, const float* __restrict__ bias0,
    const float* __restrict__ st, short* __restrict__ A2, float* __restrict__ uu) {
  int w = threadIdx.x >> 6, lane = threadIdx.x & 63;
  int n = blockIdx.x * 4 + w;
  if (n >= NN) return;
  int half = lane >> 5, ll = lane & 31;
  int c0 = (ll < 25 ? ll : 24) * 8;
  int idx = half * NN + n;
  const short* xb = X1 + (size_t)half * 400 + c0;   // + row*800 per edge

  float attv[8], xrv[8], num[8];
  {
    f32x4 a0 = (f32x4){0,0,0,0}, a1 = (f32x4){0,0,0,0};
    if (ll < 25) { a0 = *(const f32x4*)(att + c0); a1 = *(const f32x4*)(att + c0 + 4); }
#pragma unroll
    for (int q = 0; q < 4; ++q) { attv[q] = a0[q]; attv[4 + q] = a1[q]; }
    short8 xr8 = *(const short8*)(X1 + (size_t)(2 * n + half) * 400 + 200 + c0);
#pragma unroll
    for (int q = 0; q < 8; ++q) xrv[q] = (ll < 25) ? b2f(xr8[q]) : 0.f;
  }
  float m, denom = 1.f;
  { // self-loop (src = n)
    short8 v = *(const short8*)(xb + (size_t)(2 * n) * 400);
    float e = 0.f;
#pragma unroll
    for (int q = 0; q < 8; ++q) {
      float x = b2f(v[q]);
      num[q] = x;
      float msg = x + xrv[q];
      msg = (msg > 0.f) ? msg : NEG * msg;
      e = fmaf(msg, attv[q], e);
    }
#pragma unroll
    for (int off = 16; off > 0; off >>= 1) e += __shfl_xor(e, off);
    m = e;
  }

  int beg = rowptr[n], end = rowptr[n + 1];
  for (int base = beg; base < end; base += 64) {
    int cnt = min(end - base, 64);
    int cv = col[base + (lane < cnt ? lane : 0)];
    int p = 0;
    for (; p + 2 <= cnt; p += 2) {
      int s0 = __shfl(cv, p), s1 = __shfl(cv, p + 1);
      short8 v0 = *(const short8*)(xb + (size_t)(2 * s0) * 400);
      short8 v1 = *(const short8*)(xb + (size_t)(2 * s1) * 400);
      float xs0[8], xs1[8];
      float e0 = 0.f, e1 = 0.f;
#pragma unroll
      for (int q = 0; q < 8; ++q) {
        xs0[q] = b2f(v0[q]);
        float m0_ = xs0[q] + xrv[q]; m0_ = (m0_ > 0.f) ? m0_ : NEG * m0_;
        e0 = fmaf(m0_, attv[q], e0);
        xs1[q] = b2f(v1[q]);
        float m1_ = xs1[q] + xrv[q]; m1_ = (m1_ > 0.f) ? m1_ : NEG * m1_;
        e1 = fmaf(m1_, attv[q], e1);
      }
#pragma unroll
      for (int off = 16; off > 0; off >>= 1) {
        e0 += __shfl_xor(e0, off);
        e1 += __shfl_xor(e1, off);
      }
      float d0 = e0 - m;
      if (d0 > THR) {
        float so = __expf(-d0); denom *= so;
#pragma unroll
        for (int q = 0; q < 8; ++q) num[q] *= so;
        m = e0; d0 = 0.f;
      }
      float pe0 = __expf(d0);
      denom += pe0;
#pragma unroll
      for (int q = 0; q < 8; ++q) num[q] = fmaf(pe0, xs0[q], num[q]);
      float d1 = e1 - m;
      if (d1 > THR) {
        float so = __expf(-d1); denom *= so;
#pragma unroll
        for (int q = 0; q < 8; ++q) num[q] *= so;
        m = e1; d1 = 0.f;
      }
      float pe1 = __expf(d1);
      denom += pe1;
#pragma unroll
      for (int q = 0; q < 8; ++q) num[q] = fmaf(pe1, xs1[q], num[q]);
    }
    if (p < cnt) {
      int s0 = __shfl(cv, p);
      short8 v0 = *(const short8*)(xb + (size_t)(2 * s0) * 400);
      float xs0[8];
      float e0 = 0.f;
#pragma unroll
      for (int q = 0; q < 8; ++q) {
        xs0[q] = b2f(v0[q]);
        float m0_ = xs0[q] + xrv[q]; m0_ = (m0_ > 0.f) ? m0_ : NEG * m0_;
        e0 = fmaf(m0_, attv[q], e0);
      }
#pragma unroll
      for (int off = 16; off > 0; off >>= 1) e0 += __shfl_xor(e0, off);
      float d0 = e0 - m;
      if (d0 > THR) {
        float so = __expf(-d0); denom *= so;
#pragma unroll
        for (int q = 0; q < 8; ++q) num[q] *= so;
        m = e0; d0 = 0.f;
      }
      float pe0 = __expf(d0);
      denom += pe0;
#pragma unroll
      for (int q = 0; q < 8; ++q) num[q] = fmaf(pe0, xs0[q], num[q]);
    }
  }

  float invd = 1.f / denom;
  if (ll < 25) {
    f32x4 g0 = *(const f32x4*)(bgv + c0),   g1 = *(const f32x4*)(bgv + c0 + 4);
    f32x4 h0 = *(const f32x4*)(bias0 + c0), h1 = *(const f32x4*)(bias0 + c0 + 4);
    float vq[8];
#pragma unroll
    for (int q = 0; q < 4; ++q) {
      float o0 = fmaf(num[q], invd, g0[q] + h0[q]);
      vq[q] = 1.f / (1.f + __expf(-o0));
      float o1 = fmaf(num[4 + q], invd, g1[q] + h1[q]);
      vq[4 + q] = 1.f / (1.f + __expf(-o1));
    }
    size_t sb = (size_t)idx * UU;
    if (ll < 12) {                       // 8 r*state channels -> A2 granule ll
      f32x4 s0 = *(const f32x4*)(st + sb + c0), s1 = *(const f32x4*)(st + sb + c0 + 4);
      short8 wv;
#pragma unroll
      for (int q = 0; q < 4; ++q) { wv[q] = f2b(vq[q] * s0[q]); wv[4 + q] = f2b(vq[4 + q] * s1[q]); }
      *(short8*)(A2 + (size_t)idx * 128 + ((ll ^ (idx & 7)) << 3)) = wv;
    } else if (ll == 12) {               // ch 96-99 rs, 100-103 u
      f32x4 s0 = *(const f32x4*)(st + sb + 96);
      short4v wv;
#pragma unroll
      for (int q = 0; q < 4; ++q) wv[q] = f2b(vq[q] * s0[q]);
      *(short4v*)(A2 + (size_t)idx * 128 + ((12 ^ (idx & 7)) << 3)) = wv;
      *(f32x4*)(uu + sb) = (f32x4){vq[4], vq[5], vq[6], vq[7]};
    } else {                             // 8 u channels
      int uo = c0 - 100;
      *(f32x4*)(uu + sb + uo)     = (f32x4){vq[0], vq[1], vq[2], vq[3]};
      *(f32x4*)(uu + sb + uo + 4) = (f32x4){vq[4], vq[5], vq[6], vq[7]};
    }
  }
}

__global__ __launch_bounds__(256) void k_agg2(
    const short* __restrict__ X2, const int* __restrict__ rowptr, const int* __restrict__ col,
    const float* __restrict__ att, const float* __restrict__ bgv, const float* __restrict__ bias1,
    const float* __restrict__ st, float* __restrict__ out) {
  int w = threadIdx.x >> 6, lane = threadIdx.x & 63;
  int n = blockIdx.x * 4 + w;
  if (n >= NN) return;
  int half = lane >> 5, ll = lane & 31;
  int c0 = (ll < 25 ? ll : 24) * 4;
  int idx = half * NN + n;
  const short* xb = X2 + (size_t)half * 200 + c0;   // + row*400 per edge

  float attv[4], xrv[4], num[4];
  {
    f32x4 a0 = (f32x4){0,0,0,0};
    if (ll < 25) a0 = *(const f32x4*)(att + c0);
#pragma unroll
    for (int q = 0; q < 4; ++q) attv[q] = a0[q];
    short4v xr4 = *(const short4v*)(X2 + (size_t)(2 * n + half) * 200 + 100 + c0);
#pragma unroll
    for (int q = 0; q < 4; ++q) xrv[q] = (ll < 25) ? b2f(xr4[q]) : 0.f;
  }
  float m, denom = 1.f;
  {
    short4v v = *(const short4v*)(xb + (size_t)(2 * n) * 200);
    float e = 0.f;
#pragma unroll
    for (int q = 0; q < 4; ++q) {
      float x = b2f(v[q]);
      num[q] = x;
      float msg = x + xrv[q];
      msg = (msg > 0.f) ? msg : NEG * msg;
      e = fmaf(msg, attv[q], e);
    }
#pragma unroll
    for (int off = 16; off > 0; off >>= 1) e += __shfl_xor(e, off);
    m = e;
  }

  int beg = rowptr[n], end = rowptr[n + 1];
  for (int base = beg; base < end; base += 64) {
    int cnt = min(end - base, 64);
    int cv = col[base + (lane < cnt ? lane : 0)];
    int p = 0;
    for (; p + 2 <= cnt; p += 2) {
      int s0 = __shfl(cv, p), s1 = __shfl(cv, p + 1);
      short4v v0 = *(const short4v*)(xb + (size_t)(2 * s0) * 200);
      short4v v1 = *(const short4v*)(xb + (size_t)(2 * s1) * 200);
      float xs0[4], xs1[4];
      float e0 = 0.f, e1 = 0.f;
#pragma unroll
      for (int q = 0; q < 4; ++q) {
        xs0[q] = b2f(v0[q]);
        float m0_ = xs0[q] + xrv[q]; m0_ = (m0_ > 0.f) ? m0_ : NEG * m0_;
        e0 = fmaf(m0_, attv[q], e0);
        xs1[q] = b2f(v1[q]);
        float m1_ = xs1[q] + xrv[q]; m1_ = (m1_ > 0.f) ? m1_ : NEG * m1_;
        e1 = fmaf(m1_, attv[q], e1);
      }
#pragma unroll
      for (int off = 16; off > 0; off >>= 1) {
        e0 += __shfl_xor(e0, off);
        e1 += __shfl_xor(e1, off);
      }
      float d0 = e0 - m;
      if (d0 > THR) {
        float so = __expf(-d0); denom *= so;
#pragma unroll
        for (int q = 0; q < 4; ++q) num[q] *= so;
        m = e0; d0 = 0.f;
      }
      float pe0 = __expf(d0);
      denom += pe0;
#pragma unroll
      for (int q = 0; q < 4; ++q) num[q] = fmaf(pe0, xs0[q], num[q]);
      float d1 = e1 - m;
      if (d1 > THR) {
        float so = __expf(-d1); denom *= so;
#pragma unroll
        for (int q = 0; q < 4; ++q) num[q] *= so;
        m = e1; d1 = 0.f;
      }
      float pe1 = __expf(d1);
      denom += pe1;
#pragma unroll
      for (int q = 0; q < 4; ++q) num[q] = fmaf(pe1, xs1[q], num[q]);
    }
    if (p < cnt) {
      int s0 = __shfl(cv, p);
      short4v v0 = *(const short4v*)(xb + (size_t)(2 * s0) * 200);
      float xs0[4];
      float e0 = 0.f;
#pragma unroll
      for (int q = 0; q < 4; ++q) {
        xs0[q] = b2f(v0[q]);
        float m0_ = xs0[q] + xrv[q]; m0_ = (m0_ > 0.f) ? m0_ : NEG * m0_;
        e0 = fmaf(m0_, attv[q], e0);
      }
#pragma unroll
      for (int off = 16; off > 0; off >>= 1) e0 += __shfl_xor(e0, off);
      float d0 = e0 - m;
      if (d0 > THR) {
        float so = __expf(-d0); denom *= so;
#pragma unroll
        for (int q = 0; q < 4; ++q) num[q] *= so;
        m = e0; d0 = 0.f;
      }
      float pe0 = __expf(d0);
      denom += pe0;
#pragma unroll
      for (int q = 0; q < 4; ++q) num[q] = fmaf(pe0, xs0[q], num[q]);
    }
  }

  float invd = 1.f / denom;
  if (ll < 25) {
    f32x4 g0 = *(const f32x4*)(bgv + c0);
    f32x4 h0 = *(const f32x4*)(bias1 + c0);
    size_t sb = (size_t)idx * UU;
    f32x4 uv = *(const f32x4*)(out + sb + c0);   // u gate parked by k_agg1
    f32x4 sv = *(const f32x4*)(st + sb + c0);
    f32x4 res;
#pragma unroll
    for (int q = 0; q < 4; ++q) {
      float o  = fmaf(num[q], invd, g0[q] + h0[q]);
      float cvh = tanhf(o);
      res[q] = uv[q] * sv[q] + (1.f - uv[q]) * cvh;
    }
    *(f32x4*)(out + sb + c0) = res;
  }
}

// ---------------- launch ----------------

extern "C" void kernel_launch(void* const* d_in, const int* in_sizes, int n_in,
                              void* d_out, int out_size, void* d_ws, size_t ws_size,
                              hipStream_t stream) {
  const float* inp  = (const float*)d_in[0];
  const float* st   = (const float*)d_in[1];
  const int*   src  = (const int*)d_in[2];
  const int*   dst  = (const int*)d_in[3];
  const float* Wl1  = (const float*)d_in[4];
  const float* bl1  = (const float*)d_in[5];
  const float* Wr1  = (const float*)d_in[6];
  const float* br1  = (const float*)d_in[7];
  const float* att1 = (const float*)d_in[8];
  const float* bg1  = (const float*)d_in[9];
  const float* bias0= (const float*)d_in[10];
  const float* Wl2  = (const float*)d_in[11];
  const float* bl2  = (const float*)d_in[12];
  const float* Wr2  = (const float*)d_in[13];
  const float* br2  = (const float*)d_in[14];
  const float* att2 = (const float*)d_in[15];
  const float* bg2  = (const float*)d_in[16];
  const float* bias1= (const float*)d_in[17];

  const int N = NN;
  const int E = in_sizes[2];   // 160000

  // ws (~43.3 MB): X1[32MB] | A[10.26MB] | BT1 | BT2 | CSR.  X2 aliases X1 front.
  short* X1  = (short*)d_ws;                       // 40000*400 (batch-interleaved rows)
  short* X2  = X1;                                 // 40000*200 (X1 dead by then)
  short* Aws = X1 + (size_t)MT * 400;              // MPAD*128
  short* BT1 = Aws + (size_t)MPAD * 128;           // 512*128
  short* BT2 = BT1 + 512 * 128;                    // 256*128
  int* rowptr = (int*)(BT2 + 256 * 128);
  int* cursor = rowptr + (N + 1);
  int* col    = cursor + N;

  // CSR of incoming real edges (self-loops handled in-agg)
  k_zero<<<(N + 255) / 256, 256, 0, stream>>>(cursor, N);
  k_hist<<<(E + 255) / 256, 256, 0, stream>>>(dst, E, cursor);
  k_scan<<<1, 1024, 0, stream>>>(cursor, rowptr, N, E);
  k_scatter<<<(E + 255) / 256, 256, 0, stream>>>(src, dst, E, cursor, col);

  // layer 1: A1 = [inp|state] ; X1 = A1 @ [Wl1|Wr1] + [bl1|br1]
  k_buildA1<<<(MT * 16 + 255) / 256, 256, 0, stream>>>(inp, st, Aws);
  k_buildBT<<<(512 * 16 + 255) / 256, 256, 0, stream>>>(Wl1, Wr1, BT1, C1, 512, 0);
  k_buildBT<<<(256 * 16 + 255) / 256, 256, 0, stream>>>(Wl2, Wr2, BT2, C2, 256, 1);
  {
    dim3 g(MPAD / 128, 4);
    k_gemm<400, 200><<<g, 256, 0, stream>>>(Aws, BT1, bl1, br1, X1);
  }
  k_agg1<<<(NN + 3) / 4, 256, 0, stream>>>(X1, rowptr, col, att1, bg1, bias0, st,
                                           Aws, (float*)d_out);
  // layer 2: A2 = [r*state | inp] (state-first; agg1 wrote r*state; fill inp + pad)
  k_fillA2<<<(MT + 255) / 256, 256, 0, stream>>>(inp, Aws);
  {
    dim3 g(MPAD / 128, 2);
    k_gemm<200, 100><<<g, 256, 0, stream>>>(Aws, BT2, bl2, br2, X2);
  }
  k_agg2<<<(NN + 3) / 4, 256, 0, stream>>>(X2, rowptr, col, att2, bg2, bias1, st,
                                           (float*)d_out);
}

// Round 7
// 195.429 us; speedup vs baseline: 1.6255x; 1.0496x over previous
//
#include <hip/hip_runtime.h>
#include <stdint.h>

typedef __attribute__((ext_vector_type(8))) short short8;   // 8 bf16 (bit pattern)
typedef __attribute__((ext_vector_type(4))) short short4v;  // 4 bf16
typedef __attribute__((ext_vector_type(4))) float f32x4;

static constexpr int BB = 2, NN = 20000, UU = 100;
static constexpr int C1 = 200, C2 = 100;
static constexpr int MT = BB * NN;       // 40000 node-rows
static constexpr int MPAD = 40064;       // 313 * 128
static constexpr float NEG = 0.2f;

__device__ __forceinline__ float b2f(short s) {
  union { uint32_t u; float f; } cv; cv.u = ((uint32_t)(uint16_t)s) << 16; return cv.f;
}
__device__ __forceinline__ short f2b(float x) {             // RNE f32->bf16
  union { float f; uint32_t u; } cv; cv.f = x;
  uint32_t r = cv.u + 0x7FFFu + ((cv.u >> 16) & 1u);
  return (short)(r >> 16);
}

#define GL2LDS(gsrc, ldst)                                                          \
  __builtin_amdgcn_global_load_lds((const __attribute__((address_space(1))) void*)(gsrc), \
                                   (__attribute__((address_space(3))) void*)(ldst), 16, 0, 0)

// ---------------- fused prep: zero cursor + build A1 + build BT1/BT2 ----------------

__global__ void k_prep(const float* __restrict__ inp, const float* __restrict__ st,
                       const float* __restrict__ Wl1, const float* __restrict__ Wr1,
                       const float* __restrict__ Wl2, const float* __restrict__ Wr2,
                       short* __restrict__ A, short* __restrict__ BT1,
                       short* __restrict__ BT2, int* __restrict__ cursor) {
  int t = blockIdx.x * 256 + threadIdx.x;
  if (t < MT * 16) {              // A1 row r: e0=inp, e1..100=state, pad 0 (swizzled)
    int r = t >> 4, g = t & 15;
    short8 v;
#pragma unroll
    for (int j = 0; j < 8; ++j) {
      int e = g * 8 + j;
      float x = 0.f;
      if (e == 0) x = inp[r];
      else if (e <= 100) x = st[(size_t)r * 100 + e - 1];
      v[j] = f2b(x);
    }
    *(short8*)(A + (size_t)r * 128 + ((g ^ (r & 7)) << 3)) = v;
  }
  if (t < 512 * 16) {             // BT1 (rot=0, SPLIT=200)
    int n = t >> 4, g = t & 15;
    short8 v;
#pragma unroll
    for (int j = 0; j < 8; ++j) {
      int k = g * 8 + j;
      float x = 0.f;
      if (k < 101 && n < 400)
        x = (n < 200) ? Wl1[(size_t)k * 200 + n] : Wr1[(size_t)k * 200 + n - 200];
      v[j] = f2b(x);
    }
    *(short8*)(BT1 + (size_t)n * 128 + ((g ^ (n & 7)) << 3)) = v;
  }
  if (t < 256 * 16) {             // BT2 (rot=1: k<100 -> W[k+1], k==100 -> W[0])
    int n = t >> 4, g = t & 15;
    short8 v;
#pragma unroll
    for (int j = 0; j < 8; ++j) {
      int k = g * 8 + j;
      int ksrc = (k < 100) ? k + 1 : ((k == 100) ? 0 : -1);
      float x = 0.f;
      if (ksrc >= 0 && n < 200)
        x = (n < 100) ? Wl2[(size_t)ksrc * 100 + n] : Wr2[(size_t)ksrc * 100 + n - 100];
      v[j] = f2b(x);
    }
    *(short8*)(BT2 + (size_t)n * 128 + ((g ^ (n & 7)) << 3)) = v;
  }
  if (t < NN) cursor[t] = 0;
}

// ---------------- CSR build ----------------

__global__ void k_hist(const int* __restrict__ dst, int E, int* __restrict__ hist) {
  int e = blockIdx.x * 256 + threadIdx.x;
  if (e < E) atomicAdd(&hist[dst[e]], 1);
}

__global__ __launch_bounds__(1024) void k_scan(int* __restrict__ histcur,
                                               int* __restrict__ rowptr, int N, int E) {
  __shared__ int part[1024];
  int t = threadIdx.x;
  int CH = (N + 1023) / 1024;
  int beg = t * CH; if (beg > N) beg = N;
  int end = beg + CH; if (end > N) end = N;
  int s = 0;
  for (int i = beg; i < end; ++i) s += histcur[i];
  part[t] = s;
  __syncthreads();
  for (int off = 1; off < 1024; off <<= 1) {
    int v = (t >= off) ? part[t - off] : 0;
    __syncthreads();
    part[t] += v;
    __syncthreads();
  }
  int base = (t == 0) ? 0 : part[t - 1];
  for (int i = beg; i < end; ++i) {
    int h = histcur[i];
    rowptr[i] = base;
    histcur[i] = base;
    base += h;
  }
  if (t == 1023) rowptr[N] = part[1023];
}

__global__ void k_scatter(const int* __restrict__ src, const int* __restrict__ dst, int E,
                          int* __restrict__ cursor, int* __restrict__ col) {
  int e = blockIdx.x * 256 + threadIdx.x;
  if (e < E) {
    int p = atomicAdd(&cursor[dst[e]], 1);
    col[p] = src[e];
  }
}

// ---------------- MFMA GEMM: pair-contiguous output ----------------
// X row (per node, 4*SPLIT shorts): [xl_b0 | xl_b1 | xr_b0 | xr_b1], SPLIT each.

template<int NOUT, int SPLIT>
__global__ __launch_bounds__(256) void k_gemm(
    const short* __restrict__ A, const short* __restrict__ BT,
    const float* __restrict__ bias_l, const float* __restrict__ bias_r,
    short* __restrict__ X) {
  __shared__ __align__(16) short As[128 * 128];
  __shared__ __align__(16) short Bs[128 * 128];
  int tid = threadIdx.x;
  int m0 = blockIdx.x * 128;
  int n0 = blockIdx.y * 128;
  {
    const short* gA = A + (size_t)m0 * 128;
    const short* gB = BT + (size_t)n0 * 128;
#pragma unroll
    for (int i = 0; i < 8; ++i) {
      GL2LDS(gA + i * 2048 + tid * 8, As + i * 2048 + tid * 8);
      GL2LDS(gB + i * 2048 + tid * 8, Bs + i * 2048 + tid * 8);
    }
  }
  __syncthreads();

  int wv = tid >> 6, lane = tid & 63;
  int m_off = (wv & 1) * 64, n_off = (wv >> 1) * 64;
  int lrow = lane & 15, lk = lane >> 4;
  f32x4 acc[4][4];
#pragma unroll
  for (int i = 0; i < 4; ++i)
#pragma unroll
    for (int j = 0; j < 4; ++j) acc[i][j] = (f32x4){0.f, 0.f, 0.f, 0.f};

#pragma unroll
  for (int kk = 0; kk < 4; ++kk) {
    int g = kk * 4 + lk;
    short8 a[4], b[4];
#pragma unroll
    for (int f = 0; f < 4; ++f) {
      int ra = m_off + f * 16 + lrow;
      a[f] = *(const short8*)(As + ra * 128 + ((g ^ (ra & 7)) << 3));
      int rb = n_off + f * 16 + lrow;
      b[f] = *(const short8*)(Bs + rb * 128 + ((g ^ (rb & 7)) << 3));
    }
#pragma unroll
    for (int i = 0; i < 4; ++i)
#pragma unroll
      for (int j = 0; j < 4; ++j)
        acc[i][j] = __builtin_amdgcn_mfma_f32_16x16x32_bf16(a[i], b[j], acc[i][j], 0, 0, 0);
  }

#pragma unroll
  for (int j = 0; j < 4; ++j) {
    int nc = n0 + n_off + j * 16 + lrow;       // output channel
    bool nok = nc < NOUT;
    float bv = 0.f;
    int coff = 0;
    if (nok) {
      bv   = (nc < SPLIT) ? bias_l[nc] : bias_r[nc - SPLIT];
      coff = (nc < SPLIT) ? nc : 2 * SPLIT + (nc - SPLIT);
    }
#pragma unroll
    for (int i = 0; i < 4; ++i) {
      int mb = m0 + m_off + i * 16 + lk * 4;
#pragma unroll
      for (int r = 0; r < 4; ++r) {
        int m = mb + r;
        if (nok && m < MT) {
          int b_   = (m >= NN) ? 1 : 0;
          int node = m - b_ * NN;
          X[(size_t)node * (4 * SPLIT) + coff + b_ * SPLIT] = f2b(acc[i][j][r] + bv);
        }
      }
    }
  }
}

// ---------------- GATv2 aggregation ----------------
// One wave per dst; lanes 0-31 = batch 0, 32-63 = batch 1. No-max softmax
// (logits bounded, fp32 exp safe) -> edges independent -> 4-edge unroll.

__global__ __launch_bounds__(256) void k_agg1(
    const short* __restrict__ X1, const int* __restrict__ rowptr, const int* __restrict__ col,
    const float* __restrict__ att, const float* __restrict__ bgv, const float* __restrict__ bias0,
    const float* __restrict__ st, const float* __restrict__ inp,
    short* __restrict__ A2, float* __restrict__ uu) {
  int w = threadIdx.x >> 6, lane = threadIdx.x & 63;
  int n = blockIdx.x * 4 + w;
  if (n >= NN) return;
  int half = lane >> 5, ll = lane & 31;
  int c0 = (ll < 25 ? ll : 24) * 8;
  int idx = half * NN + n;
  const short* xb = X1 + (size_t)half * 200 + c0;   // + s*800 per src node

  float attv[8], xrv[8], num[8];
  {
    f32x4 a0 = (f32x4){0,0,0,0}, a1 = (f32x4){0,0,0,0};
    if (ll < 25) { a0 = *(const f32x4*)(att + c0); a1 = *(const f32x4*)(att + c0 + 4); }
#pragma unroll
    for (int q = 0; q < 4; ++q) { attv[q] = a0[q]; attv[4 + q] = a1[q]; }
    short8 xr8 = *(const short8*)(X1 + (size_t)n * 800 + 400 + half * 200 + c0);
#pragma unroll
    for (int q = 0; q < 8; ++q) xrv[q] = (ll < 25) ? b2f(xr8[q]) : 0.f;
  }
  float denom;
  { // self-loop (src = n)
    short8 v = *(const short8*)(xb + (size_t)n * 800);
    float xs[8], e = 0.f;
#pragma unroll
    for (int q = 0; q < 8; ++q) {
      xs[q] = b2f(v[q]);
      float msg = xs[q] + xrv[q];
      msg = (msg > 0.f) ? msg : NEG * msg;
      e = fmaf(msg, attv[q], e);
    }
#pragma unroll
    for (int off = 16; off > 0; off >>= 1) e += __shfl_xor(e, off);
    float pe = __expf(e);
    denom = pe;
#pragma unroll
    for (int q = 0; q < 8; ++q) num[q] = pe * xs[q];
  }

  int beg = rowptr[n], end = rowptr[n + 1];
  for (int bp = beg; bp < end; bp += 64) {
    int cnt = min(end - bp, 64);
    int cv = col[bp + (lane < cnt ? lane : 0)];
    int p = 0;
    for (; p + 4 <= cnt; p += 4) {
      int s0 = __shfl(cv, p), s1 = __shfl(cv, p + 1);
      int s2 = __shfl(cv, p + 2), s3 = __shfl(cv, p + 3);
      short8 v0 = *(const short8*)(xb + (size_t)s0 * 800);
      short8 v1 = *(const short8*)(xb + (size_t)s1 * 800);
      short8 v2 = *(const short8*)(xb + (size_t)s2 * 800);
      short8 v3 = *(const short8*)(xb + (size_t)s3 * 800);
      float xs0[8], xs1[8], xs2[8], xs3[8];
      float e0 = 0.f, e1 = 0.f, e2 = 0.f, e3 = 0.f;
#pragma unroll
      for (int q = 0; q < 8; ++q) {
        float m_;
        xs0[q] = b2f(v0[q]); m_ = xs0[q] + xrv[q]; m_ = (m_ > 0.f) ? m_ : NEG * m_; e0 = fmaf(m_, attv[q], e0);
        xs1[q] = b2f(v1[q]); m_ = xs1[q] + xrv[q]; m_ = (m_ > 0.f) ? m_ : NEG * m_; e1 = fmaf(m_, attv[q], e1);
        xs2[q] = b2f(v2[q]); m_ = xs2[q] + xrv[q]; m_ = (m_ > 0.f) ? m_ : NEG * m_; e2 = fmaf(m_, attv[q], e2);
        xs3[q] = b2f(v3[q]); m_ = xs3[q] + xrv[q]; m_ = (m_ > 0.f) ? m_ : NEG * m_; e3 = fmaf(m_, attv[q], e3);
      }
#pragma unroll
      for (int off = 16; off > 0; off >>= 1) {
        e0 += __shfl_xor(e0, off);
        e1 += __shfl_xor(e1, off);
        e2 += __shfl_xor(e2, off);
        e3 += __shfl_xor(e3, off);
      }
      float pe0 = __expf(e0), pe1 = __expf(e1), pe2 = __expf(e2), pe3 = __expf(e3);
      denom += (pe0 + pe1) + (pe2 + pe3);
#pragma unroll
      for (int q = 0; q < 8; ++q)
        num[q] = fmaf(pe3, xs3[q], fmaf(pe2, xs2[q], fmaf(pe1, xs1[q], fmaf(pe0, xs0[q], num[q]))));
    }
    for (; p < cnt; ++p) {
      int s0 = __shfl(cv, p);
      short8 v0 = *(const short8*)(xb + (size_t)s0 * 800);
      float xs0[8], e0 = 0.f;
#pragma unroll
      for (int q = 0; q < 8; ++q) {
        xs0[q] = b2f(v0[q]);
        float m_ = xs0[q] + xrv[q]; m_ = (m_ > 0.f) ? m_ : NEG * m_;
        e0 = fmaf(m_, attv[q], e0);
      }
#pragma unroll
      for (int off = 16; off > 0; off >>= 1) e0 += __shfl_xor(e0, off);
      float pe0 = __expf(e0);
      denom += pe0;
#pragma unroll
      for (int q = 0; q < 8; ++q) num[q] = fmaf(pe0, xs0[q], num[q]);
    }
  }

  float invd = 1.f / denom;
  if (ll < 25) {
    f32x4 g0 = *(const f32x4*)(bgv + c0),   g1 = *(const f32x4*)(bgv + c0 + 4);
    f32x4 h0 = *(const f32x4*)(bias0 + c0), h1 = *(const f32x4*)(bias0 + c0 + 4);
    float vq[8];
#pragma unroll
    for (int q = 0; q < 4; ++q) {
      float o0 = fmaf(num[q], invd, g0[q] + h0[q]);
      vq[q] = 1.f / (1.f + __expf(-o0));
      float o1 = fmaf(num[4 + q], invd, g1[q] + h1[q]);
      vq[4 + q] = 1.f / (1.f + __expf(-o1));
    }
    size_t sb = (size_t)idx * UU;
    if (ll < 12) {                       // 8 r*state channels -> A2 granule ll
      f32x4 s0 = *(const f32x4*)(st + sb + c0), s1 = *(const f32x4*)(st + sb + c0 + 4);
      short8 wv;
#pragma unroll
      for (int q = 0; q < 4; ++q) { wv[q] = f2b(vq[q] * s0[q]); wv[4 + q] = f2b(vq[4 + q] * s1[q]); }
      *(short8*)(A2 + (size_t)idx * 128 + ((ll ^ (idx & 7)) << 3)) = wv;
    } else if (ll == 12) {               // ch 96-99 rs + elem100 = inp + pad
      f32x4 s0 = *(const f32x4*)(st + sb + 96);
      short8 wv;
#pragma unroll
      for (int q = 0; q < 4; ++q) wv[q] = f2b(vq[q] * s0[q]);
      wv[4] = f2b(inp[idx]); wv[5] = 0; wv[6] = 0; wv[7] = 0;
      *(short8*)(A2 + (size_t)idx * 128 + ((12 ^ (idx & 7)) << 3)) = wv;
      *(f32x4*)(uu + sb) = (f32x4){vq[4], vq[5], vq[6], vq[7]};
    } else {                             // 8 u channels; ll 13-15 also zero-pad A2
      int uo = c0 - 100;
      *(f32x4*)(uu + sb + uo)     = (f32x4){vq[0], vq[1], vq[2], vq[3]};
      *(f32x4*)(uu + sb + uo + 4) = (f32x4){vq[4], vq[5], vq[6], vq[7]};
      if (ll < 16) {
        short8 z = (short8){0,0,0,0,0,0,0,0};
        *(short8*)(A2 + (size_t)idx * 128 + ((ll ^ (idx & 7)) << 3)) = z;
      }
    }
  }
}

__global__ __launch_bounds__(256) void k_agg2(
    const short* __restrict__ X2, const int* __restrict__ rowptr, const int* __restrict__ col,
    const float* __restrict__ att, const float* __restrict__ bgv, const float* __restrict__ bias1,
    const float* __restrict__ st, float* __restrict__ out) {
  int w = threadIdx.x >> 6, lane = threadIdx.x & 63;
  int n = blockIdx.x * 4 + w;
  if (n >= NN) return;
  int half = lane >> 5, ll = lane & 31;
  int c0 = (ll < 25 ? ll : 24) * 4;
  int idx = half * NN + n;
  const short* xb = X2 + (size_t)half * 100 + c0;   // + s*400 per src node

  float attv[4], xrv[4], num[4];
  {
    f32x4 a0 = (f32x4){0,0,0,0};
    if (ll < 25) a0 = *(const f32x4*)(att + c0);
#pragma unroll
    for (int q = 0; q < 4; ++q) attv[q] = a0[q];
    short4v xr4 = *(const short4v*)(X2 + (size_t)n * 400 + 200 + half * 100 + c0);
#pragma unroll
    for (int q = 0; q < 4; ++q) xrv[q] = (ll < 25) ? b2f(xr4[q]) : 0.f;
  }
  float denom;
  { // self-loop
    short4v v = *(const short4v*)(xb + (size_t)n * 400);
    float xs[4], e = 0.f;
#pragma unroll
    for (int q = 0; q < 4; ++q) {
      xs[q] = b2f(v[q]);
      float msg = xs[q] + xrv[q];
      msg = (msg > 0.f) ? msg : NEG * msg;
      e = fmaf(msg, attv[q], e);
    }
#pragma unroll
    for (int off = 16; off > 0; off >>= 1) e += __shfl_xor(e, off);
    float pe = __expf(e);
    denom = pe;
#pragma unroll
    for (int q = 0; q < 4; ++q) num[q] = pe * xs[q];
  }

  int beg = rowptr[n], end = rowptr[n + 1];
  for (int bp = beg; bp < end; bp += 64) {
    int cnt = min(end - bp, 64);
    int cv = col[bp + (lane < cnt ? lane : 0)];
    int p = 0;
    for (; p + 4 <= cnt; p += 4) {
      int s0 = __shfl(cv, p), s1 = __shfl(cv, p + 1);
      int s2 = __shfl(cv, p + 2), s3 = __shfl(cv, p + 3);
      short4v v0 = *(const short4v*)(xb + (size_t)s0 * 400);
      short4v v1 = *(const short4v*)(xb + (size_t)s1 * 400);
      short4v v2 = *(const short4v*)(xb + (size_t)s2 * 400);
      short4v v3 = *(const short4v*)(xb + (size_t)s3 * 400);
      float xs0[4], xs1[4], xs2[4], xs3[4];
      float e0 = 0.f, e1 = 0.f, e2 = 0.f, e3 = 0.f;
#pragma unroll
      for (int q = 0; q < 4; ++q) {
        float m_;
        xs0[q] = b2f(v0[q]); m_ = xs0[q] + xrv[q]; m_ = (m_ > 0.f) ? m_ : NEG * m_; e0 = fmaf(m_, attv[q], e0);
        xs1[q] = b2f(v1[q]); m_ = xs1[q] + xrv[q]; m_ = (m_ > 0.f) ? m_ : NEG * m_; e1 = fmaf(m_, attv[q], e1);
        xs2[q] = b2f(v2[q]); m_ = xs2[q] + xrv[q]; m_ = (m_ > 0.f) ? m_ : NEG * m_; e2 = fmaf(m_, attv[q], e2);
        xs3[q] = b2f(v3[q]); m_ = xs3[q] + xrv[q]; m_ = (m_ > 0.f) ? m_ : NEG * m_; e3 = fmaf(m_, attv[q], e3);
      }
#pragma unroll
      for (int off = 16; off > 0; off >>= 1) {
        e0 += __shfl_xor(e0, off);
        e1 += __shfl_xor(e1, off);
        e2 += __shfl_xor(e2, off);
        e3 += __shfl_xor(e3, off);
      }
      float pe0 = __expf(e0), pe1 = __expf(e1), pe2 = __expf(e2), pe3 = __expf(e3);
      denom += (pe0 + pe1) + (pe2 + pe3);
#pragma unroll
      for (int q = 0; q < 4; ++q)
        num[q] = fmaf(pe3, xs3[q], fmaf(pe2, xs2[q], fmaf(pe1, xs1[q], fmaf(pe0, xs0[q], num[q]))));
    }
    for (; p < cnt; ++p) {
      int s0 = __shfl(cv, p);
      short4v v0 = *(const short4v*)(xb + (size_t)s0 * 400);
      float xs0[4], e0 = 0.f;
#pragma unroll
      for (int q = 0; q < 4; ++q) {
        xs0[q] = b2f(v0[q]);
        float m_ = xs0[q] + xrv[q]; m_ = (m_ > 0.f) ? m_ : NEG * m_;
        e0 = fmaf(m_, attv[q], e0);
      }
#pragma unroll
      for (int off = 16; off > 0; off >>= 1) e0 += __shfl_xor(e0, off);
      float pe0 = __expf(e0);
      denom += pe0;
#pragma unroll
      for (int q = 0; q < 4; ++q) num[q] = fmaf(pe0, xs0[q], num[q]);
    }
  }

  float invd = 1.f / denom;
  if (ll < 25) {
    f32x4 g0 = *(const f32x4*)(bgv + c0);
    f32x4 h0 = *(const f32x4*)(bias1 + c0);
    size_t sb = (size_t)idx * UU;
    f32x4 uv = *(const f32x4*)(out + sb + c0);   // u gate parked by k_agg1
    f32x4 sv = *(const f32x4*)(st + sb + c0);
    f32x4 res;
#pragma unroll
    for (int q = 0; q < 4; ++q) {
      float o   = fmaf(num[q], invd, g0[q] + h0[q]);
      float cvh = tanhf(o);
      res[q] = uv[q] * sv[q] + (1.f - uv[q]) * cvh;
    }
    *(f32x4*)(out + sb + c0) = res;
  }
}

// ---------------- launch ----------------

extern "C" void kernel_launch(void* const* d_in, const int* in_sizes, int n_in,
                              void* d_out, int out_size, void* d_ws, size_t ws_size,
                              hipStream_t stream) {
  const float* inp  = (const float*)d_in[0];
  const float* st   = (const float*)d_in[1];
  const int*   src  = (const int*)d_in[2];
  const int*   dst  = (const int*)d_in[3];
  const float* Wl1  = (const float*)d_in[4];
  const float* bl1  = (const float*)d_in[5];
  const float* Wr1  = (const float*)d_in[6];
  const float* br1  = (const float*)d_in[7];
  const float* att1 = (const float*)d_in[8];
  const float* bg1  = (const float*)d_in[9];
  const float* bias0= (const float*)d_in[10];
  const float* Wl2  = (const float*)d_in[11];
  const float* bl2  = (const float*)d_in[12];
  const float* Wr2  = (const float*)d_in[13];
  const float* br2  = (const float*)d_in[14];
  const float* att2 = (const float*)d_in[15];
  const float* bg2  = (const float*)d_in[16];
  const float* bias1= (const float*)d_in[17];

  const int N = NN;
  const int E = in_sizes[2];   // 160000

  // ws (~43.3 MB): X1[32MB] | A[10.26MB] | BT1 | BT2 | CSR.  X2 aliases X1.
  short* X1  = (short*)d_ws;                       // NN*800 (pair-contiguous rows)
  short* X2  = X1;                                 // NN*400 (X1 dead by then)
  short* Aws = X1 + (size_t)NN * 800;              // MPAD*128
  short* BT1 = Aws + (size_t)MPAD * 128;           // 512*128
  short* BT2 = BT1 + 512 * 128;                    // 256*128
  int* rowptr = (int*)(BT2 + 256 * 128);
  int* cursor = rowptr + (N + 1);
  int* col    = cursor + N;

  // prep (A1, BT1, BT2, cursor=0) then CSR of incoming edges
  k_prep<<<(MT * 16 + 255) / 256, 256, 0, stream>>>(inp, st, Wl1, Wr1, Wl2, Wr2,
                                                    Aws, BT1, BT2, cursor);
  k_hist<<<(E + 255) / 256, 256, 0, stream>>>(dst, E, cursor);
  k_scan<<<1, 1024, 0, stream>>>(cursor, rowptr, N, E);
  k_scatter<<<(E + 255) / 256, 256, 0, stream>>>(src, dst, E, cursor, col);

  // layer 1
  {
    dim3 g(MPAD / 128, 4);
    k_gemm<400, 200><<<g, 256, 0, stream>>>(Aws, BT1, bl1, br1, X1);
  }
  k_agg1<<<(NN + 3) / 4, 256, 0, stream>>>(X1, rowptr, col, att1, bg1, bias0, st, inp,
                                           Aws, (float*)d_out);
  // layer 2 (A2 = [r*state | inp | pad], fully written by agg1)
  {
    dim3 g(MPAD / 128, 2);
    k_gemm<200, 100><<<g, 256, 0, stream>>>(Aws, BT2, bl2, br2, X2);
  }
  k_agg2<<<(NN + 3) / 4, 256, 0, stream>>>(X2, rowptr, col, att2, bg2, bias1, st,
                                           (float*)d_out);
}